// Round 3
// baseline (115.781 us; speedup 1.0000x reference)
//
#include <hip/hip_runtime.h>
#include <math.h>

#define BLK 256

typedef __attribute__((ext_vector_type(8))) short s16x8;
typedef __attribute__((ext_vector_type(16))) float f32x16;

__device__ __forceinline__ float b2f(unsigned short h) {
    union { unsigned u; float f; } x; x.u = ((unsigned)h) << 16; return x.f;
}
__device__ __forceinline__ unsigned short f2b(float f) {
    union { float f; unsigned u; } x; x.f = f;
    unsigned r = x.u + 0x7fffu + ((x.u >> 16) & 1u);
    return (unsigned short)(r >> 16);
}

#define SITE(i, j) (peps + (size_t)((i) * 4 + (j)) * 2 * 1296)

// ======================= MFMA config (proven layout) ========================
// A=env (lane->m), B=tile (lane->n via rows nt*4+col), C/D: col(lane)=n,
// row=(reg&3)+8*(reg>>2)+4*(lane>>5) [m74/m101]. Wave w owns Mtiles {w,w+4}
// (w<3) / {3}; Mtile6 base 184, dedup keeps m>=192. Ntile1 keeps n>=32.
// Single batch per block. kb-outer staging keeps live VGPRs ~12 (vs 36) so
// total unified regs (64 acc AGPR + ~60 VGPR) fit the 128 cap of
// launch_bounds(...,4) WITHOUT spilling -> 4 blocks/CU, grid 1024 = 4*256
// exactly one co-resident round. (Round-1's failure = 128-cap + old
// high-pressure structure -> forced spills; this keeps demand under the cap.)

#define MFMA_PHASE(NKB, NNT, TB, TSTR) do {                                    \
    _Pragma("unroll") for (int kb = 0; kb < NKB; ++kb) {                       \
        s16x8 _bf[NNT];                                                        \
        _Pragma("unroll") for (int nt = 0; nt < NNT; ++nt)                     \
            _bf[nt] = *(const s16x8*)&(TB)[(nt*4 + col)*(TSTR) + kb*16 + q*8]; \
        _Pragma("unroll") for (int i = 0; i < 2; ++i) {                        \
            if (i < nmt) {                                                     \
                int mt = wid + 4*i; int m0 = (mt == 6) ? 184 : mt*32;          \
                s16x8 _av = *(const s16x8*)&Ebuf[(m0 + col)*56 + kb*16 + q*8]; \
                _Pragma("unroll") for (int nt = 0; nt < NNT; ++nt)             \
                    acc[i][nt] = __builtin_amdgcn_mfma_f32_32x32x16_bf16(      \
                        _av, _bf[nt], acc[i][nt], 0, 0, 0);                    \
            } } } } while (0)

// PUT uses (m, n, v) and may use EbS / T1S.
#define SCATTER(NNT, NLIM, PUT) do {                                           \
    unsigned short* EbS = Ebuf;                                                \
    float* T1S = (float*)Ebuf; (void)EbS; (void)T1S;                           \
    _Pragma("unroll") for (int i = 0; i < 2; ++i) {                            \
      if (i < nmt) {                                                           \
        int mt = wid + 4*i; int m0 = (mt == 6) ? 184 : mt*32;                  \
        _Pragma("unroll") for (int nt = 0; nt < NNT; ++nt) {                   \
            int n = nt*4 + col;                                                \
            if ((NNT == 2 && nt == 1 && n < 32) || n >= NLIM) continue;        \
            _Pragma("unroll") for (int r = 0; r < 16; ++r) {                   \
                int m = m0 + (r&3) + 8*(r>>2) + 4*q;                           \
                if (mt == 6 && m < 192) continue;                              \
                float v = acc[i][nt][r];                                       \
                PUT;                                                           \
            } } } } } while (0)

#define ACC0() do {                                                            \
    _Pragma("unroll") for (int i = 0; i < 2; ++i)                              \
    _Pragma("unroll") for (int nt = 0; nt < 2; ++nt)                           \
    _Pragma("unroll") for (int r = 0; r < 16; ++r) acc[i][nt][r] = 0.f;        \
    } while (0)

__global__ __launch_bounds__(BLK, 4)
void peps_fused(const float* __restrict__ inputs,
                const float* __restrict__ peps,
                const float* __restrict__ pepsc,
                float* __restrict__ out)
{
    // LDS 38.9 KB * 4 = 155.6 KB <= 160 KB -> LDS allows 4 blocks/CU.
    __shared__ __align__(16) unsigned short Ebuf[216 * 56];  // env bf16 [m][56]
    __shared__ __align__(16) unsigned short TA[36 * 56];     // rotating big tile
    __shared__ __align__(16) unsigned short TBt[36 * 56];    // EBT tile
    __shared__ __align__(16) unsigned short Tk6[2 * 36 * 16];// T10, T20
    __shared__ __align__(16) float CTf[936];                 // chain tiles / T13 / NT
    __shared__ float xs[32];
    __shared__ float red[52];

    const int b0  = blockIdx.x;
    const int tid = threadIdx.x;
    const int lid = tid & 63;
    const int q   = lid >> 5;
    const int col = lid & 31;
    // wave-uniform by construction (BLK multiple of 64) -> force SGPR
    const int wid = __builtin_amdgcn_readfirstlane(tid >> 6);
    const int nmt = (wid < 3) ? 2 : 1;

    f32x16 acc[2][2];

    // ---- P0: zero Ebuf (k-pads stay 0 forever), load x (scaled by 100:
    //          constant rescale, absorbed by the final normalization).
    {
        uint4* ez = (uint4*)&Ebuf[0];
        const uint4 z = make_uint4(0u, 0u, 0u, 0u);
        for (int i2 = tid; i2 < 1512; i2 += BLK) ez[i2] = z;
        if (tid < 32) xs[tid] = inputs[b0 * 32 + tid] * 100.0f;
    }
    __syncthreads();

    // ---- P1: ALL early weight gathers ------------------------------------
    for (int idx = tid; idx < 216; idx += BLK) {
        int x = idx/36, d = (idx/6)%6, r = idx%6;
        int g0 = x + d*6 + r*36, g3 = x + d*216 + r*36;
        float a, c;
        a = SITE(0,1)[g0]; c = SITE(0,1)[g0+1296];
        CTf[idx]       = xs[2]  * a + xs[3]  * c;
        a = SITE(0,2)[g0]; c = SITE(0,2)[g0+1296];
        CTf[216 + idx] = xs[4]  * a + xs[5]  * c;
        a = SITE(3,1)[g3]; c = SITE(3,1)[g3+1296];
        CTf[432 + idx] = xs[26] * a + xs[27] * c;
        a = SITE(3,2)[g3]; c = SITE(3,2)[g3+1296];
        CTf[648 + idx] = xs[28] * a + xs[29] * c;
    }
    for (int idx = tid; idx < 36; idx += BLK) {
        int x = idx/6, d = idx%6;
        float a, c;
        a = SITE(0,3)[x + d*6];   c = SITE(0,3)[x + d*6 + 1296];
        CTf[864 + idx] = xs[6]  * a + xs[7]  * c;
        a = SITE(3,3)[x + d*216]; c = SITE(3,3)[x + d*216 + 1296];
        CTf[900 + idx] = xs[30] * a + xs[31] * c;
        int u = x, r = d;
        float a0 = SITE(0,0)[r*36 + u*6],   c0 = SITE(0,0)[r*36 + u*6 + 1296];
        float a3 = SITE(3,0)[u*216 + r*36], c3 = SITE(3,0)[u*216 + r*36 + 1296];
        Ebuf[u*56 + 6  + r] = f2b(xs[0]  * a0 + xs[1]  * c0);
        Ebuf[u*56 + 18 + r] = f2b(xs[24] * a3 + xs[25] * c3);
    }
    {   // T10 / T20 (K6 tiles [36][16], k>=6 zero)
        const float *s10 = SITE(1,0), *s20 = SITE(2,0);
        for (int idx = tid; idx < 576; idx += BLK) {
            int n = idx/16, k = idx%16;
            float v00 = 0.f, v10 = 0.f;
            if (k < 6) {
                int g = k*216 + (n/6)*6 + (n%6)*36;
                float a = s10[g], c = s10[g+1296];
                v00 = xs[8]  * a + xs[9]  * c;
                a = s20[g]; c = s20[g+1296];
                v10 = xs[16] * a + xs[17] * c;
            }
            Tk6[n*16 + k]       = f2b(v00);
            Tk6[576 + n*16 + k] = f2b(v10);
        }
    }
    {   // T11 -> TA ([36][48 valid], k>=36 zero)
        const float* s = SITE(1,1);
        for (int idx = tid; idx < 1728; idx += BLK) {
            int n = idx/48, k = idx%48;
            float v0 = 0.f;
            if (k < 36) {
                int g = (k/6)*216 + (k%6) + (n/6)*6 + (n%6)*36;
                float a = s[g], c = s[g+1296];
                v0 = xs[10] * a + xs[11] * c;
            }
            TA[n*56 + k] = f2b(v0);
        }
    }
    for (int idx = tid; idx < 432; idx += BLK) {   // TBt k-pads 36..47 zero
        int n = idx/12, k = 36 + idx%12;
        TBt[n*56 + k] = 0;
    }
    __syncthreads();

    // ---- P2: chain step1 (M=6) -------------------------------------------
    for (int t2 = tid; t2 < 216; t2 += BLK) {
        int m = t2/36, n = t2%36;
        float a0 = 0.f, a3 = 0.f;
        #pragma unroll
        for (int k = 0; k < 6; ++k) {
            a0 = fmaf(b2f(Ebuf[m*56 + 6  + k]), CTf[k*36 + n],       a0);
            a3 = fmaf(b2f(Ebuf[m*56 + 18 + k]), CTf[432 + k*36 + n], a3);
        }
        int o = (m*6 + n/6)*56 + n%6;
        Ebuf[o + 12] = f2b(a0);
        Ebuf[o + 24] = f2b(a3);
    }
    __syncthreads();

    // ---- P3: chain step2 (M=36) ------------------------------------------
    for (int t2 = tid; t2 < 1296; t2 += BLK) {
        int m = t2/36, n = t2%36;
        float a0 = 0.f, a3 = 0.f;
        #pragma unroll
        for (int k = 0; k < 6; ++k) {
            a0 = fmaf(b2f(Ebuf[m*56 + 12 + k]), CTf[216 + k*36 + n], a0);
            a3 = fmaf(b2f(Ebuf[m*56 + 24 + k]), CTf[648 + k*36 + n], a3);
        }
        int o = (m*6 + n/6)*56 + n%6;
        Ebuf[o + 6]  = f2b(a0);
        Ebuf[o + 18] = f2b(a3);
    }
    __syncthreads();

    // ---- P4: chain tails: band6 -> E0 (cols 0..5); band18 -> EBT bf16 ----
    for (int t2 = tid; t2 < 1296; t2 += BLK) {
        int m = t2/6, n = t2%6;
        float a0 = 0.f, a3 = 0.f;
        #pragma unroll
        for (int k = 0; k < 6; ++k) {
            a0 = fmaf(b2f(Ebuf[m*56 + 6  + k]), CTf[864 + k*6 + n], a0);
            a3 = fmaf(b2f(Ebuf[m*56 + 18 + k]), CTf[900 + k*6 + n], a3);
        }
        Ebuf[((m % 36)*6 + n)*56 + m/36] = f2b(a0);     // E0 [(d1d2d3)][d0]
        TBt[((m % 6)*6 + n)*56 + m/6]    = f2b(a3);     // EBT [n=(d2d3)][k=(d0d1)]
    }
    __syncthreads();

    // ================= row 1 =================
    ACC0();
    MFMA_PHASE(1, 2, Tk6, 16);                               // P5: j=0 (T10)
    __syncthreads();
    SCATTER(2, 36, EbS[((m%36)*6 + n/6)*56 + (m/36)*6 + n%6] = f2b(v));  // P6
    {   // build T13 -> CTf overlay (rows 0..5, k-pads zero)
        const float* s = SITE(1,3);
        for (int idx = tid; idx < 288; idx += BLK) {
            int n = idx/48, k = idx%48;
            float v0 = 0.f;
            if (k < 36) {
                int g = (k/6)*216 + (k%6) + n*6;
                float a = s[g], c = s[g+1296];
                v0 = xs[14] * a + xs[15] * c;
            }
            ((unsigned short*)CTf)[n*56 + k] = f2b(v0);
        }
    }
    __syncthreads();
    ACC0();
    MFMA_PHASE(3, 2, TA, 56);                                // P7: j=1 (T11)
    __syncthreads();
    SCATTER(2, 36, EbS[((m%36)*6 + n/6)*56 + (m/36)*6 + n%6] = f2b(v));  // P8
    {   // build T12 -> TA (T11 dead)
        const float* s = SITE(1,2);
        for (int idx = tid; idx < 1728; idx += BLK) {
            int n = idx/48, k = idx%48;
            float v0 = 0.f;
            if (k < 36) {
                int g = (k/6)*216 + (k%6) + (n/6)*6 + (n%6)*36;
                float a = s[g], c = s[g+1296];
                v0 = xs[12] * a + xs[13] * c;
            }
            TA[n*56 + k] = f2b(v0);
        }
    }
    __syncthreads();
    ACC0();
    MFMA_PHASE(3, 2, TA, 56);                                // P9: j=2 (T12)
    __syncthreads();
    SCATTER(2, 36, EbS[((m%36)*6 + n/6)*56 + (m/36)*6 + n%6] = f2b(v));  // P10
    {   // build T21 -> TA (T12 dead)
        const float* s = SITE(2,1);
        for (int idx = tid; idx < 1728; idx += BLK) {
            int n = idx/48, k = idx%48;
            float v0 = 0.f;
            if (k < 36) {
                int g = (k/6)*216 + (k%6) + (n/6)*6 + (n%6)*36;
                float a = s[g], c = s[g+1296];
                v0 = xs[18] * a + xs[19] * c;
            }
            TA[n*56 + k] = f2b(v0);
        }
    }
    __syncthreads();
    ACC0();
    MFMA_PHASE(3, 1, (unsigned short*)CTf, 56);              // P11: j=3 (T13)
    __syncthreads();
    SCATTER(1, 6, EbS[((m%36)*6 + n)*56 + m/36] = f2b(v));   // P12: env_top
    {   // build NT -> CTf overlay (T13 dead)
        const float* s = SITE(2,3);
        for (int idx = tid; idx < 288; idx += BLK) {
            int n = idx/48, k = idx%48;
            float v0 = 0.f;
            if (k < 36) {
                int g = (k/6)*216 + (k%6)*6 + n;
                float a = s[g], c = s[g+1296];
                v0 = xs[22] * a + xs[23] * c;
            }
            ((unsigned short*)CTf)[n*56 + k] = f2b(v0);
        }
    }
    __syncthreads();

    // ================= row 2 =================
    ACC0();
    MFMA_PHASE(1, 2, (Tk6 + 576), 16);                       // P13: j=0 (T20)
    __syncthreads();
    SCATTER(2, 36, EbS[((m%36)*6 + n/6)*56 + (m/36)*6 + n%6] = f2b(v));  // P14
    __syncthreads();
    ACC0();
    MFMA_PHASE(3, 2, TA, 56);                                // P15: j=1 (T21)
    __syncthreads();
    SCATTER(2, 36, EbS[((m/6)*6 + n%6)*56 + (m%6)*6 + n/6] = f2b(v));    // P16
    __syncthreads();
    ACC0();
    MFMA_PHASE(3, 2, TBt, 56);                               // P17: R = S_pre x EB
    __syncthreads();
    SCATTER(2, 36, EbS[((m/36)*36 + (m%6)*6 + n/6)*56 + ((m/6)%6)*6 + n%6] = f2b(v)); // P18
    __syncthreads();
    ACC0();
    MFMA_PHASE(3, 1, (unsigned short*)CTf, 56);              // P19a: T1 (NT)
    __syncthreads();   // all Ebuf frag reads done before T1 overlays it
    SCATTER(1, 6, T1S[m*6 + n] = v);                         // P19b
    __syncthreads();

    // ---- P20: out[o] = sum T1 * (x20*C0 + x21*C1), pepsc read once -------
    float part[10];
    #pragma unroll
    for (int o = 0; o < 10; ++o) part[o] = 0.f;
    {
        const float* T1p = (const float*)Ebuf;
        for (int c = tid; c < 1296; c += BLK) {
            int u2 = c / 216, r2 = (c / 36) % 6, d2 = (c / 6) % 6, r1 = c % 6;
            int e6 = u2*216 + r1*36 + d2*6 + r2;
            float t1 = T1p[e6];
            #pragma unroll
            for (int o = 0; o < 10; ++o) {
                float c0 = pepsc[o * 1296 + c];
                float c1 = pepsc[(10 + o) * 1296 + c];
                part[o] = fmaf(t1, xs[20] * c0 + xs[21] * c1, part[o]);
            }
        }
    }
    #pragma unroll
    for (int off = 32; off >= 1; off >>= 1)
        #pragma unroll
        for (int o = 0; o < 10; ++o)
            part[o] += __shfl_down(part[o], off, 64);
    if (lid == 0) {
        #pragma unroll
        for (int o = 0; o < 10; ++o) red[wid * 10 + o] = part[o];
    }
    __syncthreads();
    if (tid < 10)
        red[40 + tid] = red[tid] + red[10 + tid] + red[20 + tid] + red[30 + tid];
    __syncthreads();
    if (tid == 0) {
        float n2 = 0.f;
        #pragma unroll
        for (int o = 0; o < 10; ++o) n2 += red[40 + o] * red[40 + o];
        red[50] = 1.0f / sqrtf(n2);
    }
    __syncthreads();
    if (tid < 10) out[b0 * 10 + tid] = red[40 + tid] * red[50];
}

extern "C" void kernel_launch(void* const* d_in, const int* in_sizes, int n_in,
                              void* d_out, int out_size, void* d_ws, size_t ws_size,
                              hipStream_t stream) {
    const float* inputs = (const float*)d_in[0];   // (B,4,4,2) f32
    const float* peps   = (const float*)d_in[1];   // (4,4,2,6,6,6,6) f32
    const float* pepsc  = (const float*)d_in[2];   // (2,10,6,6,6,6) f32
    float* outp = (float*)d_out;                   // (B,10) f32
    const int B = in_sizes[0] / 32;
    peps_fused<<<dim3(B), dim3(BLK), 0, stream>>>(inputs, peps, pepsc, outp);
}

// Round 4
// 111.245 us; speedup vs baseline: 1.0408x; 1.0408x over previous
//
#include <hip/hip_runtime.h>
#include <math.h>

#define BLK 512

typedef __attribute__((ext_vector_type(8))) short s16x8;
typedef __attribute__((ext_vector_type(16))) float f32x16;

__device__ __forceinline__ float b2f(unsigned short h) {
    union { unsigned u; float f; } x; x.u = ((unsigned)h) << 16; return x.f;
}
__device__ __forceinline__ unsigned short f2b(float f) {
    union { float f; unsigned u; } x; x.f = f;
    unsigned r = x.u + 0x7fffu + ((x.u >> 16) & 1u);
    return (unsigned short)(r >> 16);
}

#define SITE(i, j) (peps + (size_t)((i) * 4 + (j)) * 2 * 1296)

// ======================= MFMA config (proven layout) ========================
// A=env (lane->m), B=tile (lane->n via rows nt*4+col), C/D: col(lane)=n,
// row=(reg&3)+8*(reg>>2)+4*(lane>>5) [m74/m101]. 8 waves/block: wave w<7 owns
// Mtile w ONLY (Mtile6 base 184, dedup keeps m>=192); wave 7 idle in MFMA.
// acc[2] = 32 AGPRs (was 64 with 2 Mtiles/wave) -> unified demand ~116 <= 128
// cap of launch_bounds(512,4) WITHOUT spilling (round-3 lesson: cap below
// demand = 34MB scratch traffic). 2 blocks/CU * 8 waves = 16 waves/CU; grid
// 1024 = 2 * 512 resident -> two uniform rounds, no ragged tail. FP accum
// order per acc element unchanged (kb ascending) -> bit-identical results.

#define MFMA_PHASE(NKB, NNT, TB, TSTR) do {                                    \
    if (wid < 7) {                                                             \
        int m0 = (wid == 6) ? 184 : wid*32;                                    \
        _Pragma("unroll") for (int kb = 0; kb < NKB; ++kb) {                   \
            s16x8 _av = *(const s16x8*)&Ebuf[(m0 + col)*56 + kb*16 + q*8];     \
            _Pragma("unroll") for (int nt = 0; nt < NNT; ++nt) {               \
                s16x8 _bf = *(const s16x8*)&(TB)[(nt*4 + col)*(TSTR) + kb*16 + q*8]; \
                acc[nt] = __builtin_amdgcn_mfma_f32_32x32x16_bf16(             \
                    _av, _bf, acc[nt], 0, 0, 0);                               \
            } } } } while (0)

// PUT uses (m, n, v) and may use EbS / T1S.
#define SCATTER(NNT, NLIM, PUT) do {                                           \
    unsigned short* EbS = Ebuf;                                                \
    float* T1S = (float*)Ebuf; (void)EbS; (void)T1S;                           \
    if (wid < 7) {                                                             \
        int m0 = (wid == 6) ? 184 : wid*32;                                    \
        _Pragma("unroll") for (int nt = 0; nt < NNT; ++nt) {                   \
            int n = nt*4 + col;                                                \
            if ((NNT == 2 && nt == 1 && n < 32) || n >= NLIM) continue;        \
            _Pragma("unroll") for (int r = 0; r < 16; ++r) {                   \
                int m = m0 + (r&3) + 8*(r>>2) + 4*q;                           \
                if (wid == 6 && m < 192) continue;                             \
                float v = acc[nt][r];                                          \
                PUT;                                                           \
            } } } } while (0)

#define ACC0() do {                                                            \
    _Pragma("unroll") for (int nt = 0; nt < 2; ++nt)                           \
    _Pragma("unroll") for (int r = 0; r < 16; ++r) acc[nt][r] = 0.f;           \
    } while (0)

__global__ __launch_bounds__(BLK, 4)
void peps_fused(const float* __restrict__ inputs,
                const float* __restrict__ peps,
                const float* __restrict__ pepsc,
                float* __restrict__ out)
{
    // LDS 38.9 KB * 2 blocks = 77.8 KB <= 160 KB.
    __shared__ __align__(16) unsigned short Ebuf[216 * 56];  // env bf16 [m][56]
    __shared__ __align__(16) unsigned short TA[36 * 56];     // rotating big tile
    __shared__ __align__(16) unsigned short TBt[36 * 56];    // EBT tile
    __shared__ __align__(16) unsigned short Tk6[2 * 36 * 16];// T10, T20
    __shared__ __align__(16) float CTf[936];                 // chain tiles / T13 / NT
    __shared__ float xs[32];
    __shared__ float red[96];

    const int b0  = blockIdx.x;
    const int tid = threadIdx.x;
    const int lid = tid & 63;
    const int q   = lid >> 5;
    const int col = lid & 31;
    // wave-uniform by construction (BLK multiple of 64) -> force SGPR
    const int wid = __builtin_amdgcn_readfirstlane(tid >> 6);

    f32x16 acc[2];

    // ---- P0: zero Ebuf (k-pads stay 0 forever), load x (scaled by 100:
    //          constant rescale, absorbed by the final normalization).
    {
        uint4* ez = (uint4*)&Ebuf[0];
        const uint4 z = make_uint4(0u, 0u, 0u, 0u);
        for (int i2 = tid; i2 < 1512; i2 += BLK) ez[i2] = z;
        if (tid < 32) xs[tid] = inputs[b0 * 32 + tid] * 100.0f;
    }
    __syncthreads();

    // ---- P1: ALL early weight gathers ------------------------------------
    for (int idx = tid; idx < 216; idx += BLK) {
        int x = idx/36, d = (idx/6)%6, r = idx%6;
        int g0 = x + d*6 + r*36, g3 = x + d*216 + r*36;
        float a, c;
        a = SITE(0,1)[g0]; c = SITE(0,1)[g0+1296];
        CTf[idx]       = xs[2]  * a + xs[3]  * c;
        a = SITE(0,2)[g0]; c = SITE(0,2)[g0+1296];
        CTf[216 + idx] = xs[4]  * a + xs[5]  * c;
        a = SITE(3,1)[g3]; c = SITE(3,1)[g3+1296];
        CTf[432 + idx] = xs[26] * a + xs[27] * c;
        a = SITE(3,2)[g3]; c = SITE(3,2)[g3+1296];
        CTf[648 + idx] = xs[28] * a + xs[29] * c;
    }
    for (int idx = tid; idx < 36; idx += BLK) {
        int x = idx/6, d = idx%6;
        float a, c;
        a = SITE(0,3)[x + d*6];   c = SITE(0,3)[x + d*6 + 1296];
        CTf[864 + idx] = xs[6]  * a + xs[7]  * c;
        a = SITE(3,3)[x + d*216]; c = SITE(3,3)[x + d*216 + 1296];
        CTf[900 + idx] = xs[30] * a + xs[31] * c;
        int u = x, r = d;
        float a0 = SITE(0,0)[r*36 + u*6],   c0 = SITE(0,0)[r*36 + u*6 + 1296];
        float a3 = SITE(3,0)[u*216 + r*36], c3 = SITE(3,0)[u*216 + r*36 + 1296];
        Ebuf[u*56 + 6  + r] = f2b(xs[0]  * a0 + xs[1]  * c0);
        Ebuf[u*56 + 18 + r] = f2b(xs[24] * a3 + xs[25] * c3);
    }
    {   // T10 / T20 (K6 tiles [36][16], k>=6 zero)
        const float *s10 = SITE(1,0), *s20 = SITE(2,0);
        for (int idx = tid; idx < 576; idx += BLK) {
            int n = idx/16, k = idx%16;
            float v00 = 0.f, v10 = 0.f;
            if (k < 6) {
                int g = k*216 + (n/6)*6 + (n%6)*36;
                float a = s10[g], c = s10[g+1296];
                v00 = xs[8]  * a + xs[9]  * c;
                a = s20[g]; c = s20[g+1296];
                v10 = xs[16] * a + xs[17] * c;
            }
            Tk6[n*16 + k]       = f2b(v00);
            Tk6[576 + n*16 + k] = f2b(v10);
        }
    }
    {   // T11 -> TA ([36][48 valid], k>=36 zero)
        const float* s = SITE(1,1);
        for (int idx = tid; idx < 1728; idx += BLK) {
            int n = idx/48, k = idx%48;
            float v0 = 0.f;
            if (k < 36) {
                int g = (k/6)*216 + (k%6) + (n/6)*6 + (n%6)*36;
                float a = s[g], c = s[g+1296];
                v0 = xs[10] * a + xs[11] * c;
            }
            TA[n*56 + k] = f2b(v0);
        }
    }
    for (int idx = tid; idx < 432; idx += BLK) {   // TBt k-pads 36..47 zero
        int n = idx/12, k = 36 + idx%12;
        TBt[n*56 + k] = 0;
    }
    __syncthreads();

    // ---- P2: chain step1 (M=6) -------------------------------------------
    for (int t2 = tid; t2 < 216; t2 += BLK) {
        int m = t2/36, n = t2%36;
        float a0 = 0.f, a3 = 0.f;
        #pragma unroll
        for (int k = 0; k < 6; ++k) {
            a0 = fmaf(b2f(Ebuf[m*56 + 6  + k]), CTf[k*36 + n],       a0);
            a3 = fmaf(b2f(Ebuf[m*56 + 18 + k]), CTf[432 + k*36 + n], a3);
        }
        int o = (m*6 + n/6)*56 + n%6;
        Ebuf[o + 12] = f2b(a0);
        Ebuf[o + 24] = f2b(a3);
    }
    __syncthreads();

    // ---- P3: chain step2 (M=36) ------------------------------------------
    for (int t2 = tid; t2 < 1296; t2 += BLK) {
        int m = t2/36, n = t2%36;
        float a0 = 0.f, a3 = 0.f;
        #pragma unroll
        for (int k = 0; k < 6; ++k) {
            a0 = fmaf(b2f(Ebuf[m*56 + 12 + k]), CTf[216 + k*36 + n], a0);
            a3 = fmaf(b2f(Ebuf[m*56 + 24 + k]), CTf[648 + k*36 + n], a3);
        }
        int o = (m*6 + n/6)*56 + n%6;
        Ebuf[o + 6]  = f2b(a0);
        Ebuf[o + 18] = f2b(a3);
    }
    __syncthreads();

    // ---- P4: chain tails: band6 -> E0 (cols 0..5); band18 -> EBT bf16 ----
    for (int t2 = tid; t2 < 1296; t2 += BLK) {
        int m = t2/6, n = t2%6;
        float a0 = 0.f, a3 = 0.f;
        #pragma unroll
        for (int k = 0; k < 6; ++k) {
            a0 = fmaf(b2f(Ebuf[m*56 + 6  + k]), CTf[864 + k*6 + n], a0);
            a3 = fmaf(b2f(Ebuf[m*56 + 18 + k]), CTf[900 + k*6 + n], a3);
        }
        Ebuf[((m % 36)*6 + n)*56 + m/36] = f2b(a0);     // E0 [(d1d2d3)][d0]
        TBt[((m % 6)*6 + n)*56 + m/6]    = f2b(a3);     // EBT [n=(d2d3)][k=(d0d1)]
    }
    __syncthreads();

    // ================= row 1 =================
    ACC0();
    MFMA_PHASE(1, 2, Tk6, 16);                               // P5: j=0 (T10)
    __syncthreads();
    SCATTER(2, 36, EbS[((m%36)*6 + n/6)*56 + (m/36)*6 + n%6] = f2b(v));  // P6
    {   // build T13 -> CTf overlay (rows 0..5, k-pads zero)
        const float* s = SITE(1,3);
        for (int idx = tid; idx < 288; idx += BLK) {
            int n = idx/48, k = idx%48;
            float v0 = 0.f;
            if (k < 36) {
                int g = (k/6)*216 + (k%6) + n*6;
                float a = s[g], c = s[g+1296];
                v0 = xs[14] * a + xs[15] * c;
            }
            ((unsigned short*)CTf)[n*56 + k] = f2b(v0);
        }
    }
    __syncthreads();
    ACC0();
    MFMA_PHASE(3, 2, TA, 56);                                // P7: j=1 (T11)
    __syncthreads();
    SCATTER(2, 36, EbS[((m%36)*6 + n/6)*56 + (m/36)*6 + n%6] = f2b(v));  // P8
    {   // build T12 -> TA (T11 dead)
        const float* s = SITE(1,2);
        for (int idx = tid; idx < 1728; idx += BLK) {
            int n = idx/48, k = idx%48;
            float v0 = 0.f;
            if (k < 36) {
                int g = (k/6)*216 + (k%6) + (n/6)*6 + (n%6)*36;
                float a = s[g], c = s[g+1296];
                v0 = xs[12] * a + xs[13] * c;
            }
            TA[n*56 + k] = f2b(v0);
        }
    }
    __syncthreads();
    ACC0();
    MFMA_PHASE(3, 2, TA, 56);                                // P9: j=2 (T12)
    __syncthreads();
    SCATTER(2, 36, EbS[((m%36)*6 + n/6)*56 + (m/36)*6 + n%6] = f2b(v));  // P10
    {   // build T21 -> TA (T12 dead)
        const float* s = SITE(2,1);
        for (int idx = tid; idx < 1728; idx += BLK) {
            int n = idx/48, k = idx%48;
            float v0 = 0.f;
            if (k < 36) {
                int g = (k/6)*216 + (k%6) + (n/6)*6 + (n%6)*36;
                float a = s[g], c = s[g+1296];
                v0 = xs[18] * a + xs[19] * c;
            }
            TA[n*56 + k] = f2b(v0);
        }
    }
    __syncthreads();
    ACC0();
    MFMA_PHASE(3, 1, (unsigned short*)CTf, 56);              // P11: j=3 (T13)
    __syncthreads();
    SCATTER(1, 6, EbS[((m%36)*6 + n)*56 + m/36] = f2b(v));   // P12: env_top
    {   // build NT -> CTf overlay (T13 dead)
        const float* s = SITE(2,3);
        for (int idx = tid; idx < 288; idx += BLK) {
            int n = idx/48, k = idx%48;
            float v0 = 0.f;
            if (k < 36) {
                int g = (k/6)*216 + (k%6)*6 + n;
                float a = s[g], c = s[g+1296];
                v0 = xs[22] * a + xs[23] * c;
            }
            ((unsigned short*)CTf)[n*56 + k] = f2b(v0);
        }
    }
    __syncthreads();

    // ================= row 2 =================
    ACC0();
    MFMA_PHASE(1, 2, (Tk6 + 576), 16);                       // P13: j=0 (T20)
    __syncthreads();
    SCATTER(2, 36, EbS[((m%36)*6 + n/6)*56 + (m/36)*6 + n%6] = f2b(v));  // P14
    __syncthreads();
    ACC0();
    MFMA_PHASE(3, 2, TA, 56);                                // P15: j=1 (T21)
    __syncthreads();
    SCATTER(2, 36, EbS[((m/6)*6 + n%6)*56 + (m%6)*6 + n/6] = f2b(v));    // P16
    __syncthreads();
    ACC0();
    MFMA_PHASE(3, 2, TBt, 56);                               // P17: R = S_pre x EB
    __syncthreads();
    SCATTER(2, 36, EbS[((m/36)*36 + (m%6)*6 + n/6)*56 + ((m/6)%6)*6 + n%6] = f2b(v)); // P18
    __syncthreads();
    ACC0();
    MFMA_PHASE(3, 1, (unsigned short*)CTf, 56);              // P19a: T1 (NT)
    __syncthreads();   // all Ebuf frag reads done before T1 overlays it
    SCATTER(1, 6, T1S[m*6 + n] = v);                         // P19b
    __syncthreads();

    // ---- P20: out[o] = sum T1 * (x20*C0 + x21*C1), pepsc read once -------
    float part[10];
    #pragma unroll
    for (int o = 0; o < 10; ++o) part[o] = 0.f;
    {
        const float* T1p = (const float*)Ebuf;
        for (int c = tid; c < 1296; c += BLK) {
            int u2 = c / 216, r2 = (c / 36) % 6, d2 = (c / 6) % 6, r1 = c % 6;
            int e6 = u2*216 + r1*36 + d2*6 + r2;
            float t1 = T1p[e6];
            #pragma unroll
            for (int o = 0; o < 10; ++o) {
                float c0 = pepsc[o * 1296 + c];
                float c1 = pepsc[(10 + o) * 1296 + c];
                part[o] = fmaf(t1, xs[20] * c0 + xs[21] * c1, part[o]);
            }
        }
    }
    #pragma unroll
    for (int off = 32; off >= 1; off >>= 1)
        #pragma unroll
        for (int o = 0; o < 10; ++o)
            part[o] += __shfl_down(part[o], off, 64);
    if (lid == 0) {
        #pragma unroll
        for (int o = 0; o < 10; ++o) red[wid * 10 + o] = part[o];
    }
    __syncthreads();
    if (tid < 10) {
        float s = 0.f;
        #pragma unroll
        for (int w = 0; w < 8; ++w) s += red[w * 10 + tid];
        red[80 + tid] = s;
    }
    __syncthreads();
    if (tid == 0) {
        float n2 = 0.f;
        #pragma unroll
        for (int o = 0; o < 10; ++o) n2 += red[80 + o] * red[80 + o];
        red[90] = 1.0f / sqrtf(n2);
    }
    __syncthreads();
    if (tid < 10) out[b0 * 10 + tid] = red[80 + tid] * red[90];
}

extern "C" void kernel_launch(void* const* d_in, const int* in_sizes, int n_in,
                              void* d_out, int out_size, void* d_ws, size_t ws_size,
                              hipStream_t stream) {
    const float* inputs = (const float*)d_in[0];   // (B,4,4,2) f32
    const float* peps   = (const float*)d_in[1];   // (4,4,2,6,6,6,6) f32
    const float* pepsc  = (const float*)d_in[2];   // (2,10,6,6,6,6) f32
    float* outp = (float*)d_out;                   // (B,10) f32
    const int B = in_sizes[0] / 32;
    peps_fused<<<dim3(B), dim3(BLK), 0, stream>>>(inputs, peps, pepsc, outp);
}

// Round 5
// 99.555 us; speedup vs baseline: 1.1630x; 1.1174x over previous
//
#include <hip/hip_runtime.h>
#include <math.h>

#define BLK 512

typedef __attribute__((ext_vector_type(8))) short s16x8;
typedef __attribute__((ext_vector_type(16))) float f32x16;
typedef __attribute__((ext_vector_type(4))) unsigned short u16x4;

__device__ __forceinline__ float b2f(unsigned short h) {
    union { unsigned u; float f; } x; x.u = ((unsigned)h) << 16; return x.f;
}
__device__ __forceinline__ unsigned short f2b(float f) {
    union { float f; unsigned u; } x; x.f = f;
    unsigned r = x.u + 0x7fffu + ((x.u >> 16) & 1u);
    return (unsigned short)(r >> 16);
}

#define SITE(i, j) (peps + (size_t)((i) * 4 + (j)) * 2 * 1296)

// ======================= MFMA config (proven layout) ========================
// A=env (lane->m), B=tile (lane->n via rows nt*4+col), C/D: col(lane)=n,
// row=(reg&3)+8*(reg>>2)+4*(lane>>5) [m74/m101]. 8 waves/block: wave w<7 owns
// Mtile w ONLY (Mtile6 base 184, dedup keeps m>=192 == skip rr=0); wave 7
// idle in MFMA. acc[2]=32 AGPR; unified ~75 regs << 128 cap of (512,4).
// Scatter addressing: off_bytes = mtab[m] + noff(n); the four scatter
// mappings are separable in m and n, so a 216-entry u16 LDS table per
// mapping replaces the per-element div/mod chains. f2b pairs replaced by
// v_cvt_pk_bf16_f32 (RNE, bit-identical to f2b).

#define MFMA_PHASE(NKB, NNT, TB, TSTR) do {                                    \
    if (wid < 7) {                                                             \
        int m0 = (wid == 6) ? 184 : wid*32;                                    \
        _Pragma("unroll") for (int kb = 0; kb < NKB; ++kb) {                   \
            s16x8 _av = *(const s16x8*)&Ebuf[(m0 + col)*56 + kb*16 + q*8];     \
            _Pragma("unroll") for (int nt = 0; nt < NNT; ++nt) {               \
                s16x8 _bf = *(const s16x8*)&(TB)[(nt*4 + col)*(TSTR) + kb*16 + q*8]; \
                acc[nt] = __builtin_amdgcn_mfma_f32_32x32x16_bf16(             \
                    _av, _bf, acc[nt], 0, 0, 0);                               \
            } } } } while (0)

// Fast scatter: NOFFE is an expression in n giving the BYTE n-offset.
// Writes bf16 via cvt_pk pairs at (char*)Ebuf + mtab[m] + noff.
#define SCAT(NNT, MTAB, NOFFE) do {                                            \
    if (wid < 7) {                                                             \
        int mbase = ((wid == 6) ? 184 : wid*32) + 4*q;                         \
        int noffv[2]; bool okv[2];                                             \
        _Pragma("unroll") for (int nt = 0; nt < NNT; ++nt) {                   \
            int n = nt*4 + col;                                                \
            noffv[nt] = (NOFFE);                                               \
            okv[nt]   = (nt == 0) || (n >= 32);                                \
        }                                                                      \
        _Pragma("unroll") for (int rr = 0; rr < 4; ++rr) {                     \
            if (wid == 6 && rr == 0) continue;                                 \
            u16x4 mt4 = *(const u16x4*)&(MTAB)[mbase + 8*rr];                  \
            _Pragma("unroll") for (int nt = 0; nt < NNT; ++nt) {               \
                _Pragma("unroll") for (int jp = 0; jp < 2; ++jp) {             \
                    unsigned pk;                                               \
                    float _lo = acc[nt][rr*4 + jp*2];                          \
                    float _hi = acc[nt][rr*4 + jp*2 + 1];                      \
                    asm("v_cvt_pk_bf16_f32 %0, %1, %2"                         \
                        : "=v"(pk) : "v"(_lo), "v"(_hi));                      \
                    if (okv[nt]) {                                             \
                        *(unsigned short*)((char*)Ebuf + (int)mt4[jp*2]   + noffv[nt]) = (unsigned short)pk;         \
                        *(unsigned short*)((char*)Ebuf + (int)mt4[jp*2+1] + noffv[nt]) = (unsigned short)(pk >> 16); \
                    } } } } } } while (0)

// P12 variant: nt=0 only, keep n<6, noff = n*112 bytes, table D.
#define SCAT_D() do {                                                          \
    if (wid < 7) {                                                             \
        int mbase = ((wid == 6) ? 184 : wid*32) + 4*q;                         \
        bool ok = (col < 6);                                                   \
        int noff = col * 112;                                                  \
        _Pragma("unroll") for (int rr = 0; rr < 4; ++rr) {                     \
            if (wid == 6 && rr == 0) continue;                                 \
            u16x4 mt4 = *(const u16x4*)&mtabD[mbase + 8*rr];                   \
            _Pragma("unroll") for (int jp = 0; jp < 2; ++jp) {                 \
                unsigned pk;                                                   \
                float _lo = acc[0][rr*4 + jp*2];                               \
                float _hi = acc[0][rr*4 + jp*2 + 1];                           \
                asm("v_cvt_pk_bf16_f32 %0, %1, %2"                             \
                    : "=v"(pk) : "v"(_lo), "v"(_hi));                          \
                if (ok) {                                                      \
                    *(unsigned short*)((char*)Ebuf + (int)mt4[jp*2]   + noff) = (unsigned short)pk;         \
                    *(unsigned short*)((char*)Ebuf + (int)mt4[jp*2+1] + noff) = (unsigned short)(pk >> 16); \
                } } } } } while (0)

// Generic scatter kept for P19b (float writes, affine index, cheap).
#define SCATTER(NNT, NLIM, PUT) do {                                           \
    unsigned short* EbS = Ebuf;                                                \
    float* T1S = (float*)Ebuf; (void)EbS; (void)T1S;                           \
    if (wid < 7) {                                                             \
        int m0 = (wid == 6) ? 184 : wid*32;                                    \
        _Pragma("unroll") for (int nt = 0; nt < NNT; ++nt) {                   \
            int n = nt*4 + col;                                                \
            if ((NNT == 2 && nt == 1 && n < 32) || n >= NLIM) continue;        \
            _Pragma("unroll") for (int r = 0; r < 16; ++r) {                   \
                int m = m0 + (r&3) + 8*(r>>2) + 4*q;                           \
                if (wid == 6 && m < 192) continue;                             \
                float v = acc[nt][r];                                          \
                PUT;                                                           \
            } } } } while (0)

#define ACC0() do {                                                            \
    _Pragma("unroll") for (int nt = 0; nt < 2; ++nt)                           \
    _Pragma("unroll") for (int r = 0; r < 16; ++r) acc[nt][r] = 0.f;           \
    } while (0)

__global__ __launch_bounds__(BLK, 4)
void peps_fused(const float* __restrict__ inputs,
                const float* __restrict__ peps,
                const float* __restrict__ pepsc,
                float* __restrict__ out)
{
    // LDS ~40.6 KB * 2 blocks = 81.3 KB <= 160 KB.
    __shared__ __align__(16) unsigned short Ebuf[216 * 56];  // env bf16 [m][56]
    __shared__ __align__(16) unsigned short TA[36 * 56];     // rotating big tile
    __shared__ __align__(16) unsigned short TBt[36 * 56];    // EBT tile
    __shared__ __align__(16) unsigned short Tk6[2 * 36 * 16];// T10, T20
    __shared__ __align__(16) float CTf[936];                 // chain tiles / T13 / NT
    __shared__ __align__(8) unsigned short mtabA[216];       // scatter m-offset tables (bytes)
    __shared__ __align__(8) unsigned short mtabB[216];
    __shared__ __align__(8) unsigned short mtabC[216];
    __shared__ __align__(8) unsigned short mtabD[216];
    __shared__ float xs[32];
    __shared__ float red[96];

    const int b0  = blockIdx.x;
    const int tid = threadIdx.x;
    const int lid = tid & 63;
    const int q   = lid >> 5;
    const int col = lid & 31;
    // wave-uniform by construction (BLK multiple of 64) -> force SGPR
    const int wid = __builtin_amdgcn_readfirstlane(tid >> 6);

    f32x16 acc[2];

    // ---- P0: zero Ebuf (k-pads stay 0 forever), load x (scaled by 100:
    //          constant rescale, absorbed by the final normalization),
    //          build scatter offset tables (pure functions of m).
    {
        uint4* ez = (uint4*)&Ebuf[0];
        const uint4 z = make_uint4(0u, 0u, 0u, 0u);
        for (int i2 = tid; i2 < 1512; i2 += BLK) ez[i2] = z;
        if (tid < 32) xs[tid] = inputs[b0 * 32 + tid] * 100.0f;
        if (tid < 216) {
            int m = tid;
            mtabA[m] = (unsigned short)(((m%36)*336 + (m/36)*6) * 2);
            mtabB[m] = (unsigned short)(((m/6)*336 + (m%6)*6) * 2);
            mtabC[m] = (unsigned short)(((m/36)*2016 + (m%6)*336 + ((m/6)%6)*6) * 2);
            mtabD[m] = (unsigned short)(((m%36)*336 + (m/36)) * 2);
        }
    }
    __syncthreads();

    // ---- P1: ALL early weight gathers ------------------------------------
    for (int idx = tid; idx < 216; idx += BLK) {
        int x = idx/36, d = (idx/6)%6, r = idx%6;
        int g0 = x + d*6 + r*36, g3 = x + d*216 + r*36;
        float a, c;
        a = SITE(0,1)[g0]; c = SITE(0,1)[g0+1296];
        CTf[idx]       = xs[2]  * a + xs[3]  * c;
        a = SITE(0,2)[g0]; c = SITE(0,2)[g0+1296];
        CTf[216 + idx] = xs[4]  * a + xs[5]  * c;
        a = SITE(3,1)[g3]; c = SITE(3,1)[g3+1296];
        CTf[432 + idx] = xs[26] * a + xs[27] * c;
        a = SITE(3,2)[g3]; c = SITE(3,2)[g3+1296];
        CTf[648 + idx] = xs[28] * a + xs[29] * c;
    }
    for (int idx = tid; idx < 36; idx += BLK) {
        int x = idx/6, d = idx%6;
        float a, c;
        a = SITE(0,3)[x + d*6];   c = SITE(0,3)[x + d*6 + 1296];
        CTf[864 + idx] = xs[6]  * a + xs[7]  * c;
        a = SITE(3,3)[x + d*216]; c = SITE(3,3)[x + d*216 + 1296];
        CTf[900 + idx] = xs[30] * a + xs[31] * c;
        int u = x, r = d;
        float a0 = SITE(0,0)[r*36 + u*6],   c0 = SITE(0,0)[r*36 + u*6 + 1296];
        float a3 = SITE(3,0)[u*216 + r*36], c3 = SITE(3,0)[u*216 + r*36 + 1296];
        Ebuf[u*56 + 6  + r] = f2b(xs[0]  * a0 + xs[1]  * c0);
        Ebuf[u*56 + 18 + r] = f2b(xs[24] * a3 + xs[25] * c3);
    }
    {   // T10 / T20 (K6 tiles [36][16], k>=6 zero)
        const float *s10 = SITE(1,0), *s20 = SITE(2,0);
        for (int idx = tid; idx < 576; idx += BLK) {
            int n = idx/16, k = idx%16;
            float v00 = 0.f, v10 = 0.f;
            if (k < 6) {
                int g = k*216 + (n/6)*6 + (n%6)*36;
                float a = s10[g], c = s10[g+1296];
                v00 = xs[8]  * a + xs[9]  * c;
                a = s20[g]; c = s20[g+1296];
                v10 = xs[16] * a + xs[17] * c;
            }
            Tk6[n*16 + k]       = f2b(v00);
            Tk6[576 + n*16 + k] = f2b(v10);
        }
    }
    {   // T11 -> TA ([36][48 valid], k>=36 zero)
        const float* s = SITE(1,1);
        for (int idx = tid; idx < 1728; idx += BLK) {
            int n = idx/48, k = idx%48;
            float v0 = 0.f;
            if (k < 36) {
                int g = (k/6)*216 + (k%6) + (n/6)*6 + (n%6)*36;
                float a = s[g], c = s[g+1296];
                v0 = xs[10] * a + xs[11] * c;
            }
            TA[n*56 + k] = f2b(v0);
        }
    }
    for (int idx = tid; idx < 432; idx += BLK) {   // TBt k-pads 36..47 zero
        int n = idx/12, k = 36 + idx%12;
        TBt[n*56 + k] = 0;
    }
    __syncthreads();

    // ---- P2: chain step1 (M=6) -------------------------------------------
    for (int t2 = tid; t2 < 216; t2 += BLK) {
        int m = t2/36, n = t2%36;
        float a0 = 0.f, a3 = 0.f;
        #pragma unroll
        for (int k = 0; k < 6; ++k) {
            a0 = fmaf(b2f(Ebuf[m*56 + 6  + k]), CTf[k*36 + n],       a0);
            a3 = fmaf(b2f(Ebuf[m*56 + 18 + k]), CTf[432 + k*36 + n], a3);
        }
        int o = (m*6 + n/6)*56 + n%6;
        Ebuf[o + 12] = f2b(a0);
        Ebuf[o + 24] = f2b(a3);
    }
    __syncthreads();

    // ---- P3: chain step2 (M=36) ------------------------------------------
    for (int t2 = tid; t2 < 1296; t2 += BLK) {
        int m = t2/36, n = t2%36;
        float a0 = 0.f, a3 = 0.f;
        #pragma unroll
        for (int k = 0; k < 6; ++k) {
            a0 = fmaf(b2f(Ebuf[m*56 + 12 + k]), CTf[216 + k*36 + n], a0);
            a3 = fmaf(b2f(Ebuf[m*56 + 24 + k]), CTf[648 + k*36 + n], a3);
        }
        int o = (m*6 + n/6)*56 + n%6;
        Ebuf[o + 6]  = f2b(a0);
        Ebuf[o + 18] = f2b(a3);
    }
    __syncthreads();

    // ---- P4: chain tails: band6 -> E0 (cols 0..5); band18 -> EBT bf16 ----
    for (int t2 = tid; t2 < 1296; t2 += BLK) {
        int m = t2/6, n = t2%6;
        float a0 = 0.f, a3 = 0.f;
        #pragma unroll
        for (int k = 0; k < 6; ++k) {
            a0 = fmaf(b2f(Ebuf[m*56 + 6  + k]), CTf[864 + k*6 + n], a0);
            a3 = fmaf(b2f(Ebuf[m*56 + 18 + k]), CTf[900 + k*6 + n], a3);
        }
        Ebuf[((m % 36)*6 + n)*56 + m/36] = f2b(a0);     // E0 [(d1d2d3)][d0]
        TBt[((m % 6)*6 + n)*56 + m/6]    = f2b(a3);     // EBT [n=(d2d3)][k=(d0d1)]
    }
    __syncthreads();

    // ================= row 1 =================
    ACC0();
    MFMA_PHASE(1, 2, Tk6, 16);                               // P5: j=0 (T10)
    __syncthreads();
    SCAT(2, mtabA, ((n/6)*56 + n%6)*2);                      // P6
    {   // build T13 -> CTf overlay (rows 0..5, k-pads zero)
        const float* s = SITE(1,3);
        for (int idx = tid; idx < 288; idx += BLK) {
            int n = idx/48, k = idx%48;
            float v0 = 0.f;
            if (k < 36) {
                int g = (k/6)*216 + (k%6) + n*6;
                float a = s[g], c = s[g+1296];
                v0 = xs[14] * a + xs[15] * c;
            }
            ((unsigned short*)CTf)[n*56 + k] = f2b(v0);
        }
    }
    __syncthreads();
    ACC0();
    MFMA_PHASE(3, 2, TA, 56);                                // P7: j=1 (T11)
    __syncthreads();
    SCAT(2, mtabA, ((n/6)*56 + n%6)*2);                      // P8
    {   // build T12 -> TA (T11 dead)
        const float* s = SITE(1,2);
        for (int idx = tid; idx < 1728; idx += BLK) {
            int n = idx/48, k = idx%48;
            float v0 = 0.f;
            if (k < 36) {
                int g = (k/6)*216 + (k%6) + (n/6)*6 + (n%6)*36;
                float a = s[g], c = s[g+1296];
                v0 = xs[12] * a + xs[13] * c;
            }
            TA[n*56 + k] = f2b(v0);
        }
    }
    __syncthreads();
    ACC0();
    MFMA_PHASE(3, 2, TA, 56);                                // P9: j=2 (T12)
    __syncthreads();
    SCAT(2, mtabA, ((n/6)*56 + n%6)*2);                      // P10
    {   // build T21 -> TA (T12 dead)
        const float* s = SITE(2,1);
        for (int idx = tid; idx < 1728; idx += BLK) {
            int n = idx/48, k = idx%48;
            float v0 = 0.f;
            if (k < 36) {
                int g = (k/6)*216 + (k%6) + (n/6)*6 + (n%6)*36;
                float a = s[g], c = s[g+1296];
                v0 = xs[18] * a + xs[19] * c;
            }
            TA[n*56 + k] = f2b(v0);
        }
    }
    __syncthreads();
    ACC0();
    MFMA_PHASE(3, 1, (unsigned short*)CTf, 56);              // P11: j=3 (T13)
    __syncthreads();
    SCAT_D();                                                // P12: env_top
    {   // build NT -> CTf overlay (T13 dead)
        const float* s = SITE(2,3);
        for (int idx = tid; idx < 288; idx += BLK) {
            int n = idx/48, k = idx%48;
            float v0 = 0.f;
            if (k < 36) {
                int g = (k/6)*216 + (k%6)*6 + n;
                float a = s[g], c = s[g+1296];
                v0 = xs[22] * a + xs[23] * c;
            }
            ((unsigned short*)CTf)[n*56 + k] = f2b(v0);
        }
    }
    __syncthreads();

    // ================= row 2 =================
    ACC0();
    MFMA_PHASE(1, 2, (Tk6 + 576), 16);                       // P13: j=0 (T20)
    __syncthreads();
    SCAT(2, mtabA, ((n/6)*56 + n%6)*2);                      // P14
    __syncthreads();
    ACC0();
    MFMA_PHASE(3, 2, TA, 56);                                // P15: j=1 (T21)
    __syncthreads();
    SCAT(2, mtabB, ((n%6)*56 + n/6)*2);                      // P16
    __syncthreads();
    ACC0();
    MFMA_PHASE(3, 2, TBt, 56);                               // P17: R = S_pre x EB
    __syncthreads();
    SCAT(2, mtabC, ((n/6)*56 + n%6)*2);                      // P18
    __syncthreads();
    ACC0();
    MFMA_PHASE(3, 1, (unsigned short*)CTf, 56);              // P19a: T1 (NT)
    __syncthreads();   // all Ebuf frag reads done before T1 overlays it
    SCATTER(1, 6, T1S[m*6 + n] = v);                         // P19b
    __syncthreads();

    // ---- P20: out[o] = sum T1 * (x20*C0 + x21*C1), pepsc read once -------
    float part[10];
    #pragma unroll
    for (int o = 0; o < 10; ++o) part[o] = 0.f;
    {
        const float* T1p = (const float*)Ebuf;
        for (int c = tid; c < 1296; c += BLK) {
            int u2 = c / 216, r2 = (c / 36) % 6, d2 = (c / 6) % 6, r1 = c % 6;
            int e6 = u2*216 + r1*36 + d2*6 + r2;
            float t1 = T1p[e6];
            #pragma unroll
            for (int o = 0; o < 10; ++o) {
                float c0 = pepsc[o * 1296 + c];
                float c1 = pepsc[(10 + o) * 1296 + c];
                part[o] = fmaf(t1, xs[20] * c0 + xs[21] * c1, part[o]);
            }
        }
    }
    #pragma unroll
    for (int off = 32; off >= 1; off >>= 1)
        #pragma unroll
        for (int o = 0; o < 10; ++o)
            part[o] += __shfl_down(part[o], off, 64);
    if (lid == 0) {
        #pragma unroll
        for (int o = 0; o < 10; ++o) red[wid * 10 + o] = part[o];
    }
    __syncthreads();
    if (tid < 10) {
        float s = 0.f;
        #pragma unroll
        for (int w = 0; w < 8; ++w) s += red[w * 10 + tid];
        red[80 + tid] = s;
    }
    __syncthreads();
    if (tid == 0) {
        float n2 = 0.f;
        #pragma unroll
        for (int o = 0; o < 10; ++o) n2 += red[80 + o] * red[80 + o];
        red[90] = 1.0f / sqrtf(n2);
    }
    __syncthreads();
    if (tid < 10) out[b0 * 10 + tid] = red[80 + tid] * red[90];
}

extern "C" void kernel_launch(void* const* d_in, const int* in_sizes, int n_in,
                              void* d_out, int out_size, void* d_ws, size_t ws_size,
                              hipStream_t stream) {
    const float* inputs = (const float*)d_in[0];   // (B,4,4,2) f32
    const float* peps   = (const float*)d_in[1];   // (4,4,2,6,6,6,6) f32
    const float* pepsc  = (const float*)d_in[2];   // (2,10,6,6,6,6) f32
    float* outp = (float*)d_out;                   // (B,10) f32
    const int B = in_sizes[0] / 32;
    peps_fused<<<dim3(B), dim3(BLK), 0, stream>>>(inputs, peps, pepsc, outp);
}

// Round 6
// 94.614 us; speedup vs baseline: 1.2237x; 1.0522x over previous
//
#include <hip/hip_runtime.h>
#include <math.h>

#define BLK 512

typedef __attribute__((ext_vector_type(8))) short s16x8;
typedef __attribute__((ext_vector_type(16))) float f32x16;
typedef __attribute__((ext_vector_type(4))) unsigned short u16x4;

__device__ __forceinline__ float b2f(unsigned short h) {
    union { unsigned u; float f; } x; x.u = ((unsigned)h) << 16; return x.f;
}
__device__ __forceinline__ unsigned short f2b(float f) {
    union { float f; unsigned u; } x; x.f = f;
    unsigned r = x.u + 0x7fffu + ((x.u >> 16) & 1u);
    return (unsigned short)(r >> 16);
}

#define SITE(i, j) (peps + (size_t)((i) * 4 + (j)) * 2 * 1296)

// ======================= MFMA config (proven layout) ========================
// A=env (lane->m), B=tile (lane->n via rows nt*4+col), C/D: col(lane)=n,
// row=(reg&3)+8*(reg>>2)+4*(lane>>5) [m74/m101]. 8 waves/block: wave w<7 owns
// Mtile w ONLY (Mtile6 base 184, dedup keeps m>=192 == skip rr=0); wave 7
// idle in MFMA. acc[2]=32 AGPR. launch_bounds(512,8): unified cap 64 regs
// (32 acc AGPR + <=32 VGPR). Per-region peak liveness ~52 (MFMA phase), so
// demand fits the cap (round-3 lesson: cap BELOW demand = spills; here it
// isn't). LDS 40960 B exactly -> 4 blocks/CU * 40960 = 163840 = full pool.
// 32 waves/CU; grid 1024 = 4*256 -> ONE co-resident round.
// Scatter addressing: off_bytes = mtab[m] + noff(n); four separable
// mappings -> 216-entry u16 LDS tables replace per-element div/mod.
// f2b pairs done via v_cvt_pk_bf16_f32 (RNE, bit-identical to f2b).

#define MFMA_PHASE(NKB, NNT, TB, TSTR) do {                                    \
    if (wid < 7) {                                                             \
        int m0 = (wid == 6) ? 184 : wid*32;                                    \
        _Pragma("unroll") for (int kb = 0; kb < NKB; ++kb) {                   \
            s16x8 _av = *(const s16x8*)&Ebuf[(m0 + col)*56 + kb*16 + q*8];     \
            _Pragma("unroll") for (int nt = 0; nt < NNT; ++nt) {               \
                s16x8 _bf = *(const s16x8*)&(TB)[(nt*4 + col)*(TSTR) + kb*16 + q*8]; \
                acc[nt] = __builtin_amdgcn_mfma_f32_32x32x16_bf16(             \
                    _av, _bf, acc[nt], 0, 0, 0);                               \
            } } } } while (0)

// Fast scatter: NOFFE is an expression in n giving the BYTE n-offset.
// Writes bf16 via cvt_pk pairs at (char*)Ebuf + mtab[m] + noff.
#define SCAT(NNT, MTAB, NOFFE) do {                                            \
    if (wid < 7) {                                                             \
        int mbase = ((wid == 6) ? 184 : wid*32) + 4*q;                         \
        int noffv[2]; bool okv[2];                                             \
        _Pragma("unroll") for (int nt = 0; nt < NNT; ++nt) {                   \
            int n = nt*4 + col;                                                \
            noffv[nt] = (NOFFE);                                               \
            okv[nt]   = (nt == 0) || (n >= 32);                                \
        }                                                                      \
        _Pragma("unroll") for (int rr = 0; rr < 4; ++rr) {                     \
            if (wid == 6 && rr == 0) continue;                                 \
            u16x4 mt4 = *(const u16x4*)&(MTAB)[mbase + 8*rr];                  \
            _Pragma("unroll") for (int nt = 0; nt < NNT; ++nt) {               \
                _Pragma("unroll") for (int jp = 0; jp < 2; ++jp) {             \
                    unsigned pk;                                               \
                    float _lo = acc[nt][rr*4 + jp*2];                          \
                    float _hi = acc[nt][rr*4 + jp*2 + 1];                      \
                    asm("v_cvt_pk_bf16_f32 %0, %1, %2"                         \
                        : "=v"(pk) : "v"(_lo), "v"(_hi));                      \
                    if (okv[nt]) {                                             \
                        *(unsigned short*)((char*)Ebuf + (int)mt4[jp*2]   + noffv[nt]) = (unsigned short)pk;         \
                        *(unsigned short*)((char*)Ebuf + (int)mt4[jp*2+1] + noffv[nt]) = (unsigned short)(pk >> 16); \
                    } } } } } } while (0)

// P12 variant: nt=0 only, keep n<6, noff = n*112 bytes, table D.
#define SCAT_D() do {                                                          \
    if (wid < 7) {                                                             \
        int mbase = ((wid == 6) ? 184 : wid*32) + 4*q;                         \
        bool ok = (col < 6);                                                   \
        int noff = col * 112;                                                  \
        _Pragma("unroll") for (int rr = 0; rr < 4; ++rr) {                     \
            if (wid == 6 && rr == 0) continue;                                 \
            u16x4 mt4 = *(const u16x4*)&mtabD[mbase + 8*rr];                   \
            _Pragma("unroll") for (int jp = 0; jp < 2; ++jp) {                 \
                unsigned pk;                                                   \
                float _lo = acc[0][rr*4 + jp*2];                               \
                float _hi = acc[0][rr*4 + jp*2 + 1];                           \
                asm("v_cvt_pk_bf16_f32 %0, %1, %2"                             \
                    : "=v"(pk) : "v"(_lo), "v"(_hi));                          \
                if (ok) {                                                      \
                    *(unsigned short*)((char*)Ebuf + (int)mt4[jp*2]   + noff) = (unsigned short)pk;         \
                    *(unsigned short*)((char*)Ebuf + (int)mt4[jp*2+1] + noff) = (unsigned short)(pk >> 16); \
                } } } } } while (0)

// Generic scatter kept for P19b (float writes, affine index, cheap).
#define SCATTER(NNT, NLIM, PUT) do {                                           \
    unsigned short* EbS = Ebuf;                                                \
    float* T1S = (float*)Ebuf; (void)EbS; (void)T1S;                           \
    if (wid < 7) {                                                             \
        int m0 = (wid == 6) ? 184 : wid*32;                                    \
        _Pragma("unroll") for (int nt = 0; nt < NNT; ++nt) {                   \
            int n = nt*4 + col;                                                \
            if ((NNT == 2 && nt == 1 && n < 32) || n >= NLIM) continue;        \
            _Pragma("unroll") for (int r = 0; r < 16; ++r) {                   \
                int m = m0 + (r&3) + 8*(r>>2) + 4*q;                           \
                if (wid == 6 && m < 192) continue;                             \
                float v = acc[nt][r];                                          \
                PUT;                                                           \
            } } } } while (0)

#define ACC0() do {                                                            \
    _Pragma("unroll") for (int nt = 0; nt < 2; ++nt)                           \
    _Pragma("unroll") for (int r = 0; r < 16; ++r) acc[nt][r] = 0.f;           \
    } while (0)

__global__ __launch_bounds__(BLK, 8)
void peps_fused(const float* __restrict__ inputs,
                const float* __restrict__ peps,
                const float* __restrict__ pepsc,
                float* __restrict__ out)
{
    // LDS 40960 B * 4 blocks = 163840 B = exactly the 160 KB pool.
    __shared__ __align__(16) unsigned short Ebuf[216 * 56];  // env bf16 [m][56]
    __shared__ __align__(16) unsigned short TA[36 * 56];     // rotating big tile
    __shared__ __align__(16) unsigned short TBt[36 * 56];    // EBT tile
    __shared__ __align__(16) unsigned short Tk6[2 * 36 * 16];// T10, T20
    __shared__ __align__(16) float CTf[936];                 // chain tiles / T13 / NT
    __shared__ __align__(8) unsigned short mtabA[216];       // scatter m-offset tables (bytes)
    __shared__ __align__(8) unsigned short mtabB[216];
    __shared__ __align__(8) unsigned short mtabC[216];
    __shared__ __align__(8) unsigned short mtabD[216];
    __shared__ float xs[32];
    __shared__ float red[96];

    const int b0  = blockIdx.x;
    const int tid = threadIdx.x;
    const int lid = tid & 63;
    const int q   = lid >> 5;
    const int col = lid & 31;
    // wave-uniform by construction (BLK multiple of 64) -> force SGPR
    const int wid = __builtin_amdgcn_readfirstlane(tid >> 6);

    f32x16 acc[2];

    // ---- P0: zero Ebuf (k-pads stay 0 forever), load x (scaled by 100:
    //          constant rescale, absorbed by the final normalization),
    //          build scatter offset tables (pure functions of m).
    {
        uint4* ez = (uint4*)&Ebuf[0];
        const uint4 z = make_uint4(0u, 0u, 0u, 0u);
        for (int i2 = tid; i2 < 1512; i2 += BLK) ez[i2] = z;
        if (tid < 32) xs[tid] = inputs[b0 * 32 + tid] * 100.0f;
        if (tid < 216) {
            int m = tid;
            mtabA[m] = (unsigned short)(((m%36)*336 + (m/36)*6) * 2);
            mtabB[m] = (unsigned short)(((m/6)*336 + (m%6)*6) * 2);
            mtabC[m] = (unsigned short)(((m/36)*2016 + (m%6)*336 + ((m/6)%6)*6) * 2);
            mtabD[m] = (unsigned short)(((m%36)*336 + (m/36)) * 2);
        }
    }
    __syncthreads();

    // ---- P1: ALL early weight gathers ------------------------------------
    for (int idx = tid; idx < 216; idx += BLK) {
        int x = idx/36, d = (idx/6)%6, r = idx%6;
        int g0 = x + d*6 + r*36, g3 = x + d*216 + r*36;
        float a, c;
        a = SITE(0,1)[g0]; c = SITE(0,1)[g0+1296];
        CTf[idx]       = xs[2]  * a + xs[3]  * c;
        a = SITE(0,2)[g0]; c = SITE(0,2)[g0+1296];
        CTf[216 + idx] = xs[4]  * a + xs[5]  * c;
        a = SITE(3,1)[g3]; c = SITE(3,1)[g3+1296];
        CTf[432 + idx] = xs[26] * a + xs[27] * c;
        a = SITE(3,2)[g3]; c = SITE(3,2)[g3+1296];
        CTf[648 + idx] = xs[28] * a + xs[29] * c;
    }
    for (int idx = tid; idx < 36; idx += BLK) {
        int x = idx/6, d = idx%6;
        float a, c;
        a = SITE(0,3)[x + d*6];   c = SITE(0,3)[x + d*6 + 1296];
        CTf[864 + idx] = xs[6]  * a + xs[7]  * c;
        a = SITE(3,3)[x + d*216]; c = SITE(3,3)[x + d*216 + 1296];
        CTf[900 + idx] = xs[30] * a + xs[31] * c;
        int u = x, r = d;
        float a0 = SITE(0,0)[r*36 + u*6],   c0 = SITE(0,0)[r*36 + u*6 + 1296];
        float a3 = SITE(3,0)[u*216 + r*36], c3 = SITE(3,0)[u*216 + r*36 + 1296];
        Ebuf[u*56 + 6  + r] = f2b(xs[0]  * a0 + xs[1]  * c0);
        Ebuf[u*56 + 18 + r] = f2b(xs[24] * a3 + xs[25] * c3);
    }
    {   // T10 / T20 (K6 tiles [36][16], k>=6 zero)
        const float *s10 = SITE(1,0), *s20 = SITE(2,0);
        for (int idx = tid; idx < 576; idx += BLK) {
            int n = idx/16, k = idx%16;
            float v00 = 0.f, v10 = 0.f;
            if (k < 6) {
                int g = k*216 + (n/6)*6 + (n%6)*36;
                float a = s10[g], c = s10[g+1296];
                v00 = xs[8]  * a + xs[9]  * c;
                a = s20[g]; c = s20[g+1296];
                v10 = xs[16] * a + xs[17] * c;
            }
            Tk6[n*16 + k]       = f2b(v00);
            Tk6[576 + n*16 + k] = f2b(v10);
        }
    }
    {   // T11 -> TA ([36][48 valid], k>=36 zero)
        const float* s = SITE(1,1);
        for (int idx = tid; idx < 1728; idx += BLK) {
            int n = idx/48, k = idx%48;
            float v0 = 0.f;
            if (k < 36) {
                int g = (k/6)*216 + (k%6) + (n/6)*6 + (n%6)*36;
                float a = s[g], c = s[g+1296];
                v0 = xs[10] * a + xs[11] * c;
            }
            TA[n*56 + k] = f2b(v0);
        }
    }
    for (int idx = tid; idx < 432; idx += BLK) {   // TBt k-pads 36..47 zero
        int n = idx/12, k = 36 + idx%12;
        TBt[n*56 + k] = 0;
    }
    __syncthreads();

    // ---- P2: chain step1 (M=6) -------------------------------------------
    for (int t2 = tid; t2 < 216; t2 += BLK) {
        int m = t2/36, n = t2%36;
        float a0 = 0.f, a3 = 0.f;
        #pragma unroll
        for (int k = 0; k < 6; ++k) {
            a0 = fmaf(b2f(Ebuf[m*56 + 6  + k]), CTf[k*36 + n],       a0);
            a3 = fmaf(b2f(Ebuf[m*56 + 18 + k]), CTf[432 + k*36 + n], a3);
        }
        int o = (m*6 + n/6)*56 + n%6;
        Ebuf[o + 12] = f2b(a0);
        Ebuf[o + 24] = f2b(a3);
    }
    __syncthreads();

    // ---- P3: chain step2 (M=36) ------------------------------------------
    for (int t2 = tid; t2 < 1296; t2 += BLK) {
        int m = t2/36, n = t2%36;
        float a0 = 0.f, a3 = 0.f;
        #pragma unroll
        for (int k = 0; k < 6; ++k) {
            a0 = fmaf(b2f(Ebuf[m*56 + 12 + k]), CTf[216 + k*36 + n], a0);
            a3 = fmaf(b2f(Ebuf[m*56 + 24 + k]), CTf[648 + k*36 + n], a3);
        }
        int o = (m*6 + n/6)*56 + n%6;
        Ebuf[o + 6]  = f2b(a0);
        Ebuf[o + 18] = f2b(a3);
    }
    __syncthreads();

    // ---- P4: chain tails: band6 -> E0 (cols 0..5); band18 -> EBT bf16 ----
    for (int t2 = tid; t2 < 1296; t2 += BLK) {
        int m = t2/6, n = t2%6;
        float a0 = 0.f, a3 = 0.f;
        #pragma unroll
        for (int k = 0; k < 6; ++k) {
            a0 = fmaf(b2f(Ebuf[m*56 + 6  + k]), CTf[864 + k*6 + n], a0);
            a3 = fmaf(b2f(Ebuf[m*56 + 18 + k]), CTf[900 + k*6 + n], a3);
        }
        Ebuf[((m % 36)*6 + n)*56 + m/36] = f2b(a0);     // E0 [(d1d2d3)][d0]
        TBt[((m % 6)*6 + n)*56 + m/6]    = f2b(a3);     // EBT [n=(d2d3)][k=(d0d1)]
    }
    __syncthreads();

    // ================= row 1 =================
    ACC0();
    MFMA_PHASE(1, 2, Tk6, 16);                               // P5: j=0 (T10)
    __syncthreads();
    SCAT(2, mtabA, ((n/6)*56 + n%6)*2);                      // P6
    {   // build T13 -> CTf overlay (rows 0..5, k-pads zero)
        const float* s = SITE(1,3);
        for (int idx = tid; idx < 288; idx += BLK) {
            int n = idx/48, k = idx%48;
            float v0 = 0.f;
            if (k < 36) {
                int g = (k/6)*216 + (k%6) + n*6;
                float a = s[g], c = s[g+1296];
                v0 = xs[14] * a + xs[15] * c;
            }
            ((unsigned short*)CTf)[n*56 + k] = f2b(v0);
        }
    }
    __syncthreads();
    ACC0();
    MFMA_PHASE(3, 2, TA, 56);                                // P7: j=1 (T11)
    __syncthreads();
    SCAT(2, mtabA, ((n/6)*56 + n%6)*2);                      // P8
    {   // build T12 -> TA (T11 dead)
        const float* s = SITE(1,2);
        for (int idx = tid; idx < 1728; idx += BLK) {
            int n = idx/48, k = idx%48;
            float v0 = 0.f;
            if (k < 36) {
                int g = (k/6)*216 + (k%6) + (n/6)*6 + (n%6)*36;
                float a = s[g], c = s[g+1296];
                v0 = xs[12] * a + xs[13] * c;
            }
            TA[n*56 + k] = f2b(v0);
        }
    }
    __syncthreads();
    ACC0();
    MFMA_PHASE(3, 2, TA, 56);                                // P9: j=2 (T12)
    __syncthreads();
    SCAT(2, mtabA, ((n/6)*56 + n%6)*2);                      // P10
    {   // build T21 -> TA (T12 dead)
        const float* s = SITE(2,1);
        for (int idx = tid; idx < 1728; idx += BLK) {
            int n = idx/48, k = idx%48;
            float v0 = 0.f;
            if (k < 36) {
                int g = (k/6)*216 + (k%6) + (n/6)*6 + (n%6)*36;
                float a = s[g], c = s[g+1296];
                v0 = xs[18] * a + xs[19] * c;
            }
            TA[n*56 + k] = f2b(v0);
        }
    }
    __syncthreads();
    ACC0();
    MFMA_PHASE(3, 1, (unsigned short*)CTf, 56);              // P11: j=3 (T13)
    __syncthreads();
    SCAT_D();                                                // P12: env_top
    {   // build NT -> CTf overlay (T13 dead)
        const float* s = SITE(2,3);
        for (int idx = tid; idx < 288; idx += BLK) {
            int n = idx/48, k = idx%48;
            float v0 = 0.f;
            if (k < 36) {
                int g = (k/6)*216 + (k%6)*6 + n;
                float a = s[g], c = s[g+1296];
                v0 = xs[22] * a + xs[23] * c;
            }
            ((unsigned short*)CTf)[n*56 + k] = f2b(v0);
        }
    }
    __syncthreads();

    // ================= row 2 =================
    ACC0();
    MFMA_PHASE(1, 2, (Tk6 + 576), 16);                       // P13: j=0 (T20)
    __syncthreads();
    SCAT(2, mtabA, ((n/6)*56 + n%6)*2);                      // P14
    __syncthreads();
    ACC0();
    MFMA_PHASE(3, 2, TA, 56);                                // P15: j=1 (T21)
    __syncthreads();
    SCAT(2, mtabB, ((n%6)*56 + n/6)*2);                      // P16
    __syncthreads();
    ACC0();
    MFMA_PHASE(3, 2, TBt, 56);                               // P17: R = S_pre x EB
    __syncthreads();
    SCAT(2, mtabC, ((n/6)*56 + n%6)*2);                      // P18
    __syncthreads();
    ACC0();
    MFMA_PHASE(3, 1, (unsigned short*)CTf, 56);              // P19a: T1 (NT)
    __syncthreads();   // all Ebuf frag reads done before T1 overlays it
    SCATTER(1, 6, T1S[m*6 + n] = v);                         // P19b
    __syncthreads();

    // ---- P20: out[o] = sum T1 * (x20*C0 + x21*C1), pepsc read once -------
    float part[10];
    #pragma unroll
    for (int o = 0; o < 10; ++o) part[o] = 0.f;
    {
        const float* T1p = (const float*)Ebuf;
        for (int c = tid; c < 1296; c += BLK) {
            int u2 = c / 216, r2 = (c / 36) % 6, d2 = (c / 6) % 6, r1 = c % 6;
            int e6 = u2*216 + r1*36 + d2*6 + r2;
            float t1 = T1p[e6];
            #pragma unroll
            for (int o = 0; o < 10; ++o) {
                float c0 = pepsc[o * 1296 + c];
                float c1 = pepsc[(10 + o) * 1296 + c];
                part[o] = fmaf(t1, xs[20] * c0 + xs[21] * c1, part[o]);
            }
        }
    }
    #pragma unroll
    for (int off = 32; off >= 1; off >>= 1)
        #pragma unroll
        for (int o = 0; o < 10; ++o)
            part[o] += __shfl_down(part[o], off, 64);
    if (lid == 0) {
        #pragma unroll
        for (int o = 0; o < 10; ++o) red[wid * 10 + o] = part[o];
    }
    __syncthreads();
    if (tid < 10) {
        float s = 0.f;
        #pragma unroll
        for (int w = 0; w < 8; ++w) s += red[w * 10 + tid];
        red[80 + tid] = s;
    }
    __syncthreads();
    if (tid == 0) {
        float n2 = 0.f;
        #pragma unroll
        for (int o = 0; o < 10; ++o) n2 += red[80 + o] * red[80 + o];
        red[90] = 1.0f / sqrtf(n2);
    }
    __syncthreads();
    if (tid < 10) out[b0 * 10 + tid] = red[80 + tid] * red[90];
}

extern "C" void kernel_launch(void* const* d_in, const int* in_sizes, int n_in,
                              void* d_out, int out_size, void* d_ws, size_t ws_size,
                              hipStream_t stream) {
    const float* inputs = (const float*)d_in[0];   // (B,4,4,2) f32
    const float* peps   = (const float*)d_in[1];   // (4,4,2,6,6,6,6) f32
    const float* pepsc  = (const float*)d_in[2];   // (2,10,6,6,6,6) f32
    float* outp = (float*)d_out;                   // (B,10) f32
    const int B = in_sizes[0] / 32;
    peps_fused<<<dim3(B), dim3(BLK), 0, stream>>>(inputs, peps, pepsc, outp);
}

// Round 7
// 92.025 us; speedup vs baseline: 1.2581x; 1.0281x over previous
//
#include <hip/hip_runtime.h>
#include <math.h>

#define BLK 512

typedef __attribute__((ext_vector_type(8))) short s16x8;
typedef __attribute__((ext_vector_type(16))) float f32x16;
typedef __attribute__((ext_vector_type(4))) unsigned short u16x4;

__device__ __forceinline__ float b2f(unsigned short h) {
    union { unsigned u; float f; } x; x.u = ((unsigned)h) << 16; return x.f;
}
__device__ __forceinline__ unsigned short f2b(float f) {
    union { float f; unsigned u; } x; x.f = f;
    unsigned r = x.u + 0x7fffu + ((x.u >> 16) & 1u);
    return (unsigned short)(r >> 16);
}

#define SITE(i, j) (peps + (size_t)((i) * 4 + (j)) * 2 * 1296)

// ===================== prep kernel: one-time gather reorder =================
// Writes d_ws: W = float2[8880] of (a,c) weight pairs pre-gathered into the
// EXACT destination order of each LDS tile (pads pre-zeroed), then
// PC = float[25920] = pepsc permuted into e6 order. Main-kernel builds become
// pure linear streams with zero index math. Layout (float2 units):
//  W11@0[2016] W12@2016 W21@4032 W13@6048[336] WNT@6384[336]
//  W10@6720[576] W20@7296[576] WCT@7872[936] WE0@8808[36] WE3@8844[36]
__global__ __launch_bounds__(256)
void peps_prep(const float* __restrict__ peps, const float* __restrict__ pepsc,
               float* __restrict__ ws)
{
    int idx = blockIdx.x * 256 + threadIdx.x;
    float2* W = (float2*)ws;
    float* PC = ws + 2 * 8880;
    if (idx < 8880) {
        const float* s = peps;
        int g = -1;
        if (idx < 6048) {
            int seg = idx / 2016, i = idx - seg * 2016;
            int n = i / 56, k = i % 56;
            s = (seg == 0) ? SITE(1,1) : (seg == 1) ? SITE(1,2) : SITE(2,1);
            if (k < 36) g = (k/6)*216 + (k%6) + (n/6)*6 + (n%6)*36;
        } else if (idx < 6384) {
            int i = idx - 6048, n = i / 56, k = i % 56;
            s = SITE(1,3);
            if (k < 36) g = (k/6)*216 + (k%6) + n*6;
        } else if (idx < 6720) {
            int i = idx - 6384, n = i / 56, k = i % 56;
            s = SITE(2,3);
            if (k < 36) g = (k/6)*216 + (k%6)*6 + n;
        } else if (idx < 7872) {
            int i = idx - 6720; int w2 = i / 576; i -= w2 * 576;
            int n = i / 16, k = i % 16;
            s = w2 ? SITE(2,0) : SITE(1,0);
            if (k < 6) g = k*216 + (n/6)*6 + (n%6)*36;
        } else if (idx < 8808) {
            int i = idx - 7872;
            if (i < 864) {
                int seg = i / 216, j = i - seg * 216;
                int x = j/36, d = (j/6)%6, r = j%6;
                if (seg == 0)      { s = SITE(0,1); g = x + d*6   + r*36; }
                else if (seg == 1) { s = SITE(0,2); g = x + d*6   + r*36; }
                else if (seg == 2) { s = SITE(3,1); g = x + d*216 + r*36; }
                else               { s = SITE(3,2); g = x + d*216 + r*36; }
            } else {
                int j = i - 864, seg = j / 36, t = j % 36;
                int x = t/6, d = t%6;
                if (seg == 0) { s = SITE(0,3); g = x + d*6; }
                else          { s = SITE(3,3); g = x + d*216; }
            }
        } else if (idx < 8844) {
            int i = idx - 8808; s = SITE(0,0); g = (i%6)*36 + (i/6)*6;
        } else {
            int i = idx - 8844; s = SITE(3,0); g = (i/6)*216 + (i%6)*36;
        }
        float a = 0.f, c = 0.f;
        if (g >= 0) { a = s[g]; c = s[g + 1296]; }
        W[idx] = make_float2(a, c);
    } else if (idx < 8880 + 25920) {
        int i = idx - 8880;
        int o = i / 1296, e = i % 1296;
        int u2 = e / 216, r1 = (e / 36) % 6, d2 = (e / 6) % 6, r2 = e % 6;
        PC[i] = pepsc[o * 1296 + u2*216 + r2*36 + d2*6 + r1];
    }
}

// ======================= MFMA config (proven layout) ========================
// A=env (lane->m), B=tile (lane->n via rows nt*4+col), C/D: col(lane)=n,
// row=(reg&3)+8*(reg>>2)+4*(lane>>5) [m74/m101]. 8 waves/block: wave w<7 owns
// Mtile w (Mtile6 base 184, dedup keeps m>=192 == skip rr=0); wave 7 idle in
// MFMA. acc[2]=32 AGPR; launch_bounds(512,8) caps unified regs at 64
// (32 AGPR + <=32 VGPR, no spill at round-6 codegen). LDS 40960 B exactly ->
// 4 blocks/CU; grid 1024 = one co-resident round.

#define MFMA_PHASE(NKB, NNT, TB, TSTR) do {                                    \
    if (wid < 7) {                                                             \
        int m0 = (wid == 6) ? 184 : wid*32;                                    \
        _Pragma("unroll") for (int kb = 0; kb < NKB; ++kb) {                   \
            s16x8 _av = *(const s16x8*)&Ebuf[(m0 + col)*56 + kb*16 + q*8];     \
            _Pragma("unroll") for (int nt = 0; nt < NNT; ++nt) {               \
                s16x8 _bf = *(const s16x8*)&(TB)[(nt*4 + col)*(TSTR) + kb*16 + q*8]; \
                acc[nt] = __builtin_amdgcn_mfma_f32_32x32x16_bf16(             \
                    _av, _bf, acc[nt], 0, 0, 0);                               \
            } } } } while (0)

// Fast scatter: off_bytes = mtab[m] + NOFFE(n); cvt_pk pairs (RNE == f2b).
#define SCAT(NNT, MTAB, NOFFE) do {                                            \
    if (wid < 7) {                                                             \
        int mbase = ((wid == 6) ? 184 : wid*32) + 4*q;                         \
        int noffv[2]; bool okv[2];                                             \
        _Pragma("unroll") for (int nt = 0; nt < NNT; ++nt) {                   \
            int n = nt*4 + col;                                                \
            noffv[nt] = (NOFFE);                                               \
            okv[nt]   = (nt == 0) || (n >= 32);                                \
        }                                                                      \
        _Pragma("unroll") for (int rr = 0; rr < 4; ++rr) {                     \
            if (wid == 6 && rr == 0) continue;                                 \
            u16x4 mt4 = *(const u16x4*)&(MTAB)[mbase + 8*rr];                  \
            _Pragma("unroll") for (int nt = 0; nt < NNT; ++nt) {               \
                _Pragma("unroll") for (int jp = 0; jp < 2; ++jp) {             \
                    unsigned pk;                                               \
                    float _lo = acc[nt][rr*4 + jp*2];                          \
                    float _hi = acc[nt][rr*4 + jp*2 + 1];                      \
                    asm("v_cvt_pk_bf16_f32 %0, %1, %2"                         \
                        : "=v"(pk) : "v"(_lo), "v"(_hi));                      \
                    if (okv[nt]) {                                             \
                        *(unsigned short*)((char*)Ebuf + (int)mt4[jp*2]   + noffv[nt]) = (unsigned short)pk;         \
                        *(unsigned short*)((char*)Ebuf + (int)mt4[jp*2+1] + noffv[nt]) = (unsigned short)(pk >> 16); \
                    } } } } } } while (0)

// P12 variant: nt=0 only, keep n<6, noff = n*112 bytes, table D.
#define SCAT_D() do {                                                          \
    if (wid < 7) {                                                             \
        int mbase = ((wid == 6) ? 184 : wid*32) + 4*q;                         \
        bool ok = (col < 6);                                                   \
        int noff = col * 112;                                                  \
        _Pragma("unroll") for (int rr = 0; rr < 4; ++rr) {                     \
            if (wid == 6 && rr == 0) continue;                                 \
            u16x4 mt4 = *(const u16x4*)&mtabD[mbase + 8*rr];                   \
            _Pragma("unroll") for (int jp = 0; jp < 2; ++jp) {                 \
                unsigned pk;                                                   \
                float _lo = acc[0][rr*4 + jp*2];                               \
                float _hi = acc[0][rr*4 + jp*2 + 1];                           \
                asm("v_cvt_pk_bf16_f32 %0, %1, %2"                             \
                    : "=v"(pk) : "v"(_lo), "v"(_hi));                          \
                if (ok) {                                                      \
                    *(unsigned short*)((char*)Ebuf + (int)mt4[jp*2]   + noff) = (unsigned short)pk;         \
                    *(unsigned short*)((char*)Ebuf + (int)mt4[jp*2+1] + noff) = (unsigned short)(pk >> 16); \
                } } } } } while (0)

// Generic scatter kept for P19b (float writes, affine index, cheap).
#define SCATTER(NNT, NLIM, PUT) do {                                           \
    unsigned short* EbS = Ebuf;                                                \
    float* T1S = (float*)Ebuf; (void)EbS; (void)T1S;                           \
    if (wid < 7) {                                                             \
        int m0 = (wid == 6) ? 184 : wid*32;                                    \
        _Pragma("unroll") for (int nt = 0; nt < NNT; ++nt) {                   \
            int n = nt*4 + col;                                                \
            if ((NNT == 2 && nt == 1 && n < 32) || n >= NLIM) continue;        \
            _Pragma("unroll") for (int r = 0; r < 16; ++r) {                   \
                int m = m0 + (r&3) + 8*(r>>2) + 4*q;                           \
                if (wid == 6 && m < 192) continue;                             \
                float v = acc[nt][r];                                          \
                PUT;                                                           \
            } } } } while (0)

#define ACC0() do {                                                            \
    _Pragma("unroll") for (int nt = 0; nt < 2; ++nt)                           \
    _Pragma("unroll") for (int r = 0; r < 16; ++r) acc[nt][r] = 0.f;           \
    } while (0)

// Linear build: DST u16 tile <- cvt_pk(X0*w.xz + X1*w.yw) over NPAIR float4.
#define BUILD2(DST, SRCF2, NPAIR, X0, X1) do {                                 \
    const float4* _w4 = (const float4*)(SRCF2);                                \
    for (int p = tid; p < (NPAIR); p += BLK) {                                 \
        float4 w = _w4[p];                                                     \
        float _lo = (X0)*w.x + (X1)*w.y, _hi = (X0)*w.z + (X1)*w.w;            \
        unsigned pk;                                                           \
        asm("v_cvt_pk_bf16_f32 %0, %1, %2" : "=v"(pk) : "v"(_lo), "v"(_hi));   \
        *(unsigned*)&(DST)[p*2] = pk;                                          \
    } } while (0)

__global__ __launch_bounds__(BLK, 8)
void peps_fused(const float* __restrict__ inputs,
                const float* __restrict__ ws,
                float* __restrict__ out)
{
    // LDS 40960 B * 4 blocks = exactly the 160 KB pool (unchanged from r6).
    __shared__ __align__(16) unsigned short Ebuf[216 * 56];  // env bf16 [m][56]
    __shared__ __align__(16) unsigned short TA[36 * 56];     // rotating big tile
    __shared__ __align__(16) unsigned short TBt[36 * 56];    // EBT tile
    __shared__ __align__(16) unsigned short Tk6[2 * 36 * 16];// T10, T20
    __shared__ __align__(16) float CTf[936];                 // chain tiles / T13 / NT
    __shared__ __align__(8) unsigned short mtabA[216];       // scatter m-offset tables (bytes)
    __shared__ __align__(8) unsigned short mtabB[216];
    __shared__ __align__(8) unsigned short mtabC[216];
    __shared__ __align__(8) unsigned short mtabD[216];
    __shared__ float xs[32];
    __shared__ float red[96];

    const int b0  = blockIdx.x;
    const int tid = threadIdx.x;
    const int lid = tid & 63;
    const int q   = lid >> 5;
    const int col = lid & 31;
    // wave-uniform by construction (BLK multiple of 64) -> force SGPR
    const int wid = __builtin_amdgcn_readfirstlane(tid >> 6);

    const float2* W = (const float2*)ws;
    const float*  PC = ws + 2 * 8880;

    f32x16 acc[2];

    // ---- P0: zero Ebuf, load x (x100 rescale, absorbed by final norm),
    //          build scatter offset tables (pure functions of m).
    {
        uint4* ez = (uint4*)&Ebuf[0];
        const uint4 z = make_uint4(0u, 0u, 0u, 0u);
        for (int i2 = tid; i2 < 1512; i2 += BLK) ez[i2] = z;
        if (tid < 32) xs[tid] = inputs[b0 * 32 + tid] * 100.0f;
        if (tid < 216) {
            int m = tid;
            mtabA[m] = (unsigned short)(((m%36)*336 + (m/36)*6) * 2);
            mtabB[m] = (unsigned short)(((m/6)*336 + (m%6)*6) * 2);
            mtabC[m] = (unsigned short)(((m/36)*2016 + (m%6)*336 + ((m/6)%6)*6) * 2);
            mtabD[m] = (unsigned short)(((m%36)*336 + (m/36)) * 2);
        }
    }
    __syncthreads();

    // ---- P1: weight tiles from prepped streams ---------------------------
    for (int idx = tid; idx < 936; idx += BLK) {   // CTf (f32 chain tiles)
        float2 w = W[7872 + idx];
        int ci = (idx < 216) ? 2 : (idx < 432) ? 4 : (idx < 648) ? 26
               : (idx < 864) ? 28 : (idx < 900) ? 6 : 30;
        CTf[idx] = xs[ci] * w.x + xs[ci + 1] * w.y;
    }
    if (tid < 36) {                                // E0 / E3 seed columns
        float2 w0 = W[8808 + tid], w3 = W[8844 + tid];
        int u = tid / 6, r = tid % 6;
        Ebuf[u*56 + 6  + r] = f2b(xs[0]  * w0.x + xs[1]  * w0.y);
        Ebuf[u*56 + 18 + r] = f2b(xs[24] * w3.x + xs[25] * w3.y);
    }
    {   // Tk6: T10 / T20 linear
        const float4* W10 = (const float4*)(W + 6720);
        const float4* W20 = (const float4*)(W + 7296);
        for (int p = tid; p < 288; p += BLK) {
            float4 w = W10[p];
            float lo = xs[8]*w.x + xs[9]*w.y, hi = xs[8]*w.z + xs[9]*w.w;
            unsigned pk;
            asm("v_cvt_pk_bf16_f32 %0, %1, %2" : "=v"(pk) : "v"(lo), "v"(hi));
            *(unsigned*)&Tk6[p*2] = pk;
            w = W20[p];
            lo = xs[16]*w.x + xs[17]*w.y; hi = xs[16]*w.z + xs[17]*w.w;
            asm("v_cvt_pk_bf16_f32 %0, %1, %2" : "=v"(pk) : "v"(lo), "v"(hi));
            *(unsigned*)&Tk6[576 + p*2] = pk;
        }
    }
    BUILD2(TA, W + 0, 1008, xs[10], xs[11]);       // T11
    for (int idx = tid; idx < 432; idx += BLK) {   // TBt k-pads 36..47 zero
        int n = idx/12, k = 36 + idx%12;
        TBt[n*56 + k] = 0;
    }
    __syncthreads();

    // ---- P2: chain step1 (M=6) -------------------------------------------
    for (int t2 = tid; t2 < 216; t2 += BLK) {
        int m = t2/36, n = t2%36;
        float a0 = 0.f, a3 = 0.f;
        #pragma unroll
        for (int k = 0; k < 6; ++k) {
            a0 = fmaf(b2f(Ebuf[m*56 + 6  + k]), CTf[k*36 + n],       a0);
            a3 = fmaf(b2f(Ebuf[m*56 + 18 + k]), CTf[432 + k*36 + n], a3);
        }
        int o = (m*6 + n/6)*56 + n%6;
        Ebuf[o + 12] = f2b(a0);
        Ebuf[o + 24] = f2b(a3);
    }
    __syncthreads();

    // ---- P3: chain step2 (M=36) ------------------------------------------
    for (int t2 = tid; t2 < 1296; t2 += BLK) {
        int m = t2/36, n = t2%36;
        float a0 = 0.f, a3 = 0.f;
        #pragma unroll
        for (int k = 0; k < 6; ++k) {
            a0 = fmaf(b2f(Ebuf[m*56 + 12 + k]), CTf[216 + k*36 + n], a0);
            a3 = fmaf(b2f(Ebuf[m*56 + 24 + k]), CTf[648 + k*36 + n], a3);
        }
        int o = (m*6 + n/6)*56 + n%6;
        Ebuf[o + 6]  = f2b(a0);
        Ebuf[o + 18] = f2b(a3);
    }
    __syncthreads();

    // ---- P4: chain tails: band6 -> E0 (cols 0..5); band18 -> EBT bf16 ----
    for (int t2 = tid; t2 < 1296; t2 += BLK) {
        int m = t2/6, n = t2%6;
        float a0 = 0.f, a3 = 0.f;
        #pragma unroll
        for (int k = 0; k < 6; ++k) {
            a0 = fmaf(b2f(Ebuf[m*56 + 6  + k]), CTf[864 + k*6 + n], a0);
            a3 = fmaf(b2f(Ebuf[m*56 + 18 + k]), CTf[900 + k*6 + n], a3);
        }
        Ebuf[((m % 36)*6 + n)*56 + m/36] = f2b(a0);     // E0 [(d1d2d3)][d0]
        TBt[((m % 6)*6 + n)*56 + m/6]    = f2b(a3);     // EBT [n=(d2d3)][k=(d0d1)]
    }
    __syncthreads();

    // ================= row 1 =================
    ACC0();
    MFMA_PHASE(1, 2, Tk6, 16);                               // P5: j=0 (T10)
    __syncthreads();
    SCAT(2, mtabA, ((n/6)*56 + n%6)*2);                      // P6
    BUILD2((unsigned short*)CTf, W + 6048, 168, xs[14], xs[15]);  // T13 overlay
    __syncthreads();
    ACC0();
    MFMA_PHASE(3, 2, TA, 56);                                // P7: j=1 (T11)
    __syncthreads();
    SCAT(2, mtabA, ((n/6)*56 + n%6)*2);                      // P8
    BUILD2(TA, W + 2016, 1008, xs[12], xs[13]);              // T12 (T11 dead)
    __syncthreads();
    ACC0();
    MFMA_PHASE(3, 2, TA, 56);                                // P9: j=2 (T12)
    __syncthreads();
    SCAT(2, mtabA, ((n/6)*56 + n%6)*2);                      // P10
    BUILD2(TA, W + 4032, 1008, xs[18], xs[19]);              // T21 (T12 dead)
    __syncthreads();
    ACC0();
    MFMA_PHASE(3, 1, (unsigned short*)CTf, 56);              // P11: j=3 (T13)
    __syncthreads();
    SCAT_D();                                                // P12: env_top
    BUILD2((unsigned short*)CTf, W + 6384, 168, xs[22], xs[23]);  // NT overlay
    __syncthreads();

    // ================= row 2 =================
    ACC0();
    MFMA_PHASE(1, 2, (Tk6 + 576), 16);                       // P13: j=0 (T20)
    __syncthreads();
    SCAT(2, mtabA, ((n/6)*56 + n%6)*2);                      // P14
    __syncthreads();
    ACC0();
    MFMA_PHASE(3, 2, TA, 56);                                // P15: j=1 (T21)
    __syncthreads();
    SCAT(2, mtabB, ((n%6)*56 + n/6)*2);                      // P16
    __syncthreads();
    ACC0();
    MFMA_PHASE(3, 2, TBt, 56);                               // P17: R = S_pre x EB
    __syncthreads();
    SCAT(2, mtabC, ((n/6)*56 + n%6)*2);                      // P18
    __syncthreads();
    ACC0();
    MFMA_PHASE(3, 1, (unsigned short*)CTf, 56);              // P19a: T1 (NT)
    __syncthreads();   // all Ebuf frag reads done before T1 overlays it
    SCATTER(1, 6, T1S[m*6 + n] = v);                         // P19b
    __syncthreads();

    // ---- P20: out[o] = sum T1 * (x20*C0 + x21*C1), PC pre-permuted -------
    float part[10];
    #pragma unroll
    for (int o = 0; o < 10; ++o) part[o] = 0.f;
    {
        const float* T1p = (const float*)Ebuf;
        for (int e = tid; e < 1296; e += BLK) {
            float t1 = T1p[e];
            #pragma unroll
            for (int o = 0; o < 10; ++o) {
                float c0 = PC[o * 1296 + e];
                float c1 = PC[(10 + o) * 1296 + e];
                part[o] = fmaf(t1, xs[20] * c0 + xs[21] * c1, part[o]);
            }
        }
    }
    #pragma unroll
    for (int off = 32; off >= 1; off >>= 1)
        #pragma unroll
        for (int o = 0; o < 10; ++o)
            part[o] += __shfl_down(part[o], off, 64);
    if (lid == 0) {
        #pragma unroll
        for (int o = 0; o < 10; ++o) red[wid * 10 + o] = part[o];
    }
    __syncthreads();
    if (tid < 10) {
        float s = 0.f;
        #pragma unroll
        for (int w = 0; w < 8; ++w) s += red[w * 10 + tid];
        red[80 + tid] = s;
    }
    __syncthreads();
    if (tid == 0) {
        float n2 = 0.f;
        #pragma unroll
        for (int o = 0; o < 10; ++o) n2 += red[80 + o] * red[80 + o];
        red[90] = 1.0f / sqrtf(n2);
    }
    __syncthreads();
    if (tid < 10) out[b0 * 10 + tid] = red[80 + tid] * red[90];
}

extern "C" void kernel_launch(void* const* d_in, const int* in_sizes, int n_in,
                              void* d_out, int out_size, void* d_ws, size_t ws_size,
                              hipStream_t stream) {
    const float* inputs = (const float*)d_in[0];   // (B,4,4,2) f32
    const float* peps   = (const float*)d_in[1];   // (4,4,2,6,6,6,6) f32
    const float* pepsc  = (const float*)d_in[2];   // (2,10,6,6,6,6) f32
    float* outp = (float*)d_out;                   // (B,10) f32
    float* ws   = (float*)d_ws;                    // >= 174,720 B used
    const int B = in_sizes[0] / 32;
    peps_prep<<<dim3(136), dim3(256), 0, stream>>>(peps, pepsc, ws);
    peps_fused<<<dim3(B), dim3(BLK), 0, stream>>>(inputs, ws, outp);
}

// Round 8
// 91.137 us; speedup vs baseline: 1.2704x; 1.0097x over previous
//
#include <hip/hip_runtime.h>
#include <math.h>

#define BLK 512

typedef __attribute__((ext_vector_type(8))) short s16x8;
typedef __attribute__((ext_vector_type(16))) float f32x16;
typedef __attribute__((ext_vector_type(4))) unsigned short u16x4;

__device__ __forceinline__ float b2f(unsigned short h) {
    union { unsigned u; float f; } x; x.u = ((unsigned)h) << 16; return x.f;
}
__device__ __forceinline__ unsigned short f2b(float f) {
    union { float f; unsigned u; } x; x.f = f;
    unsigned r = x.u + 0x7fffu + ((x.u >> 16) & 1u);
    return (unsigned short)(r >> 16);
}

#define SITE(i, j) (peps + (size_t)((i) * 4 + (j)) * 2 * 1296)

// ===================== prep kernel: one-time gather reorder =================
// Writes d_ws: W = float2[8880] of (a,c) weight pairs pre-gathered into the
// EXACT destination order of each LDS tile (pads pre-zeroed), then
// PC = float[25920] = pepsc permuted into e6 order. Layout (float2 units):
//  W11@0[2016] W12@2016 W21@4032 W13@6048[336] WNT@6384[336]
//  W10@6720[576] W20@7296[576] WCT@7872[936, k-minor n*6+k] WE0@8808[36]
//  WE3@8844[36]
__global__ __launch_bounds__(256)
void peps_prep(const float* __restrict__ peps, const float* __restrict__ pepsc,
               float* __restrict__ ws)
{
    int idx = blockIdx.x * 256 + threadIdx.x;
    float2* W = (float2*)ws;
    float* PC = ws + 2 * 8880;
    if (idx < 8880) {
        const float* s = peps;
        int g = -1;
        if (idx < 6048) {
            int seg = idx / 2016, i = idx - seg * 2016;
            int n = i / 56, k = i % 56;
            s = (seg == 0) ? SITE(1,1) : (seg == 1) ? SITE(1,2) : SITE(2,1);
            if (k < 36) g = (k/6)*216 + (k%6) + (n/6)*6 + (n%6)*36;
        } else if (idx < 6384) {
            int i = idx - 6048, n = i / 56, k = i % 56;
            s = SITE(1,3);
            if (k < 36) g = (k/6)*216 + (k%6) + n*6;
        } else if (idx < 6720) {
            int i = idx - 6384, n = i / 56, k = i % 56;
            s = SITE(2,3);
            if (k < 36) g = (k/6)*216 + (k%6)*6 + n;
        } else if (idx < 7872) {
            int i = idx - 6720; int w2 = i / 576; i -= w2 * 576;
            int n = i / 16, k = i % 16;
            s = w2 ? SITE(2,0) : SITE(1,0);
            if (k < 6) g = k*216 + (n/6)*6 + (n%6)*36;
        } else if (idx < 8808) {
            int i = idx - 7872;
            if (i < 864) {          // chain tiles, NEW k-minor order [n*6+k]
                int seg = i / 216, j = i - seg * 216;
                int n = j / 6, k = j % 6;
                if (seg == 0)      { s = SITE(0,1); g = k + (n/6)*6   + (n%6)*36; }
                else if (seg == 1) { s = SITE(0,2); g = k + (n/6)*6   + (n%6)*36; }
                else if (seg == 2) { s = SITE(3,1); g = k + (n/6)*216 + (n%6)*36; }
                else               { s = SITE(3,2); g = k + (n/6)*216 + (n%6)*36; }
            } else {                // P4 tail tiles, NEW k-minor [n*6+k]
                int j = i - 864, seg = j / 36, t = j % 36;
                int n = t / 6, k = t % 6;
                if (seg == 0) { s = SITE(0,3); g = k + n*6; }
                else          { s = SITE(3,3); g = k + n*216; }
            }
        } else if (idx < 8844) {
            int i = idx - 8808; s = SITE(0,0); g = (i%6)*36 + (i/6)*6;
        } else {
            int i = idx - 8844; s = SITE(3,0); g = (i/6)*216 + (i%6)*36;
        }
        float a = 0.f, c = 0.f;
        if (g >= 0) { a = s[g]; c = s[g + 1296]; }
        W[idx] = make_float2(a, c);
    } else if (idx < 8880 + 25920) {
        int i = idx - 8880;
        int o = i / 1296, e = i % 1296;
        int u2 = e / 216, r1 = (e / 36) % 6, d2 = (e / 6) % 6, r2 = e % 6;
        PC[i] = pepsc[o * 1296 + u2*216 + r2*36 + d2*6 + r1];
    }
}

// ======================= MFMA config (proven layout) ========================
// A=env (lane->m), B=tile (lane->n via rows nt*4+col), C/D: col(lane)=n,
// row=(reg&3)+8*(reg>>2)+4*(lane>>5) [m74/m101]. 8 waves/block: wave w<7 owns
// Mtile w (Mtile6 base 184, dedup keeps m>=192 == skip rr=0); wave 7 idle in
// MFMA. acc[2]=32 AGPR; launch_bounds(512,8) caps unified regs at 64.
// LDS 40688 B -> block size 40960 -> 4 blocks/CU; grid 1024 = one round.

#define MFMA_PHASE(NKB, NNT, TB, TSTR) do {                                    \
    if (wid < 7) {                                                             \
        int m0 = (wid == 6) ? 184 : wid*32;                                    \
        _Pragma("unroll") for (int kb = 0; kb < NKB; ++kb) {                   \
            s16x8 _av = *(const s16x8*)&Ebuf[(m0 + col)*56 + kb*16 + q*8];     \
            _Pragma("unroll") for (int nt = 0; nt < NNT; ++nt) {               \
                s16x8 _bf = *(const s16x8*)&(TB)[(nt*4 + col)*(TSTR) + kb*16 + q*8]; \
                acc[nt] = __builtin_amdgcn_mfma_f32_32x32x16_bf16(             \
                    _av, _bf, acc[nt], 0, 0, 0);                               \
            } } } } while (0)

// Fast scatter: off_bytes = mtab[m] + NOFFE(n); cvt_pk pairs (RNE == f2b).
#define SCAT(NNT, MTAB, NOFFE) do {                                            \
    if (wid < 7) {                                                             \
        int mbase = ((wid == 6) ? 184 : wid*32) + 4*q;                         \
        int noffv[2]; bool okv[2];                                             \
        _Pragma("unroll") for (int nt = 0; nt < NNT; ++nt) {                   \
            int n = nt*4 + col;                                                \
            noffv[nt] = (NOFFE);                                               \
            okv[nt]   = (nt == 0) || (n >= 32);                                \
        }                                                                      \
        _Pragma("unroll") for (int rr = 0; rr < 4; ++rr) {                     \
            if (wid == 6 && rr == 0) continue;                                 \
            u16x4 mt4 = *(const u16x4*)&(MTAB)[mbase + 8*rr];                  \
            _Pragma("unroll") for (int nt = 0; nt < NNT; ++nt) {               \
                _Pragma("unroll") for (int jp = 0; jp < 2; ++jp) {             \
                    unsigned pk;                                               \
                    float _lo = acc[nt][rr*4 + jp*2];                          \
                    float _hi = acc[nt][rr*4 + jp*2 + 1];                      \
                    asm("v_cvt_pk_bf16_f32 %0, %1, %2"                         \
                        : "=v"(pk) : "v"(_lo), "v"(_hi));                      \
                    if (okv[nt]) {                                             \
                        *(unsigned short*)((char*)Ebuf + (int)mt4[jp*2]   + noffv[nt]) = (unsigned short)pk;         \
                        *(unsigned short*)((char*)Ebuf + (int)mt4[jp*2+1] + noffv[nt]) = (unsigned short)(pk >> 16); \
                    } } } } } } while (0)

// P12 variant: nt=0 only, keep n<6, noff = n*112 bytes, table D.
#define SCAT_D() do {                                                          \
    if (wid < 7) {                                                             \
        int mbase = ((wid == 6) ? 184 : wid*32) + 4*q;                         \
        bool ok = (col < 6);                                                   \
        int noff = col * 112;                                                  \
        _Pragma("unroll") for (int rr = 0; rr < 4; ++rr) {                     \
            if (wid == 6 && rr == 0) continue;                                 \
            u16x4 mt4 = *(const u16x4*)&mtabD[mbase + 8*rr];                   \
            _Pragma("unroll") for (int jp = 0; jp < 2; ++jp) {                 \
                unsigned pk;                                                   \
                float _lo = acc[0][rr*4 + jp*2];                               \
                float _hi = acc[0][rr*4 + jp*2 + 1];                           \
                asm("v_cvt_pk_bf16_f32 %0, %1, %2"                             \
                    : "=v"(pk) : "v"(_lo), "v"(_hi));                          \
                if (ok) {                                                      \
                    *(unsigned short*)((char*)Ebuf + (int)mt4[jp*2]   + noff) = (unsigned short)pk;         \
                    *(unsigned short*)((char*)Ebuf + (int)mt4[jp*2+1] + noff) = (unsigned short)(pk >> 16); \
                } } } } } while (0)

// Generic scatter kept for P19b (float writes, affine index, cheap).
#define SCATTER(NNT, NLIM, PUT) do {                                           \
    unsigned short* EbS = Ebuf;                                                \
    float* T1S = (float*)Ebuf; (void)EbS; (void)T1S;                           \
    if (wid < 7) {                                                             \
        int m0 = (wid == 6) ? 184 : wid*32;                                    \
        _Pragma("unroll") for (int nt = 0; nt < NNT; ++nt) {                   \
            int n = nt*4 + col;                                                \
            if ((NNT == 2 && nt == 1 && n < 32) || n >= NLIM) continue;        \
            _Pragma("unroll") for (int r = 0; r < 16; ++r) {                   \
                int m = m0 + (r&3) + 8*(r>>2) + 4*q;                           \
                if (wid == 6 && m < 192) continue;                             \
                float v = acc[nt][r];                                          \
                PUT;                                                           \
            } } } } while (0)

#define ACC0() do {                                                            \
    _Pragma("unroll") for (int nt = 0; nt < 2; ++nt)                           \
    _Pragma("unroll") for (int r = 0; r < 16; ++r) acc[nt][r] = 0.f;           \
    } while (0)

// Linear build: DST u16 tile <- cvt_pk(X0*w.xz + X1*w.yw) over NPAIR float4.
#define BUILD2(DST, SRCF2, NPAIR, X0, X1) do {                                 \
    const float4* _w4 = (const float4*)(SRCF2);                                \
    for (int p = tid; p < (NPAIR); p += BLK) {                                 \
        float4 w = _w4[p];                                                     \
        float _lo = (X0)*w.x + (X1)*w.y, _hi = (X0)*w.z + (X1)*w.w;            \
        unsigned pk;                                                           \
        asm("v_cvt_pk_bf16_f32 %0, %1, %2" : "=v"(pk) : "v"(_lo), "v"(_hi));   \
        *(unsigned*)&(DST)[p*2] = pk;                                          \
    } } while (0)

__global__ __launch_bounds__(BLK, 8)
void peps_fused(const float* __restrict__ inputs,
                const float* __restrict__ ws,
                float* __restrict__ out)
{
    __shared__ __align__(16) unsigned short Ebuf[216 * 56];  // env bf16 [m][56]
    __shared__ __align__(16) unsigned short TA[36 * 56];     // rotating big tile
    __shared__ __align__(16) unsigned short TBt[36 * 56];    // EBT tile
    __shared__ __align__(16) unsigned short Tk6[2 * 36 * 16];// T10, T20
    __shared__ __align__(16) float CTf[936];                 // chain tiles (k-minor) / overlays
    __shared__ __align__(8) unsigned short mtabA[216];       // scatter m-offset tables (bytes)
    __shared__ __align__(8) unsigned short mtabB[216];
    __shared__ __align__(8) unsigned short mtabC[216];
    __shared__ __align__(8) unsigned short mtabD[216];
    __shared__ __align__(8) unsigned short seedb[72];        // E0/E3 chain seeds (bf16)
    __shared__ float xs[32];
    __shared__ float red[96];

    const int b0  = blockIdx.x;
    const int tid = threadIdx.x;
    const int lid = tid & 63;
    const int q   = lid >> 5;
    const int col = lid & 31;
    // wave-uniform by construction (BLK multiple of 64) -> force SGPR
    const int wid = __builtin_amdgcn_readfirstlane(tid >> 6);

    const float2* W = (const float2*)ws;
    const float*  PC = ws + 2 * 8880;

    f32x16 acc[2];

    // ---- P0 (merged): xs per-wave (same-wave LDS in-order => no barrier
    //      needed before in-phase xs reads; duplicate identical writes are
    //      benign), zero Ebuf, scatter tables, seeds->seedb, ALL tile builds.
    {
        if (lid < 32) xs[lid] = inputs[b0 * 32 + lid] * 100.0f;
        uint4* ez = (uint4*)&Ebuf[0];
        const uint4 z = make_uint4(0u, 0u, 0u, 0u);
        for (int i2 = tid; i2 < 1512; i2 += BLK) ez[i2] = z;
        if (tid < 216) {
            int m = tid;
            mtabA[m] = (unsigned short)(((m%36)*336 + (m/36)*6) * 2);
            mtabB[m] = (unsigned short)(((m/6)*336 + (m%6)*6) * 2);
            mtabC[m] = (unsigned short)(((m/36)*2016 + (m%6)*336 + ((m/6)%6)*6) * 2);
            mtabD[m] = (unsigned short)(((m%36)*336 + (m/36)) * 2);
        }
        if (tid < 36) {                            // chain seeds (bf16, bit-exact)
            float2 w0 = W[8808 + tid], w3 = W[8844 + tid];
            seedb[tid]      = f2b(xs[0]  * w0.x + xs[1]  * w0.y);
            seedb[36 + tid] = f2b(xs[24] * w3.x + xs[25] * w3.y);
        }
        for (int idx = tid; idx < 936; idx += BLK) {   // CTf (f32, k-minor)
            float2 w = W[7872 + idx];
            int ci = (idx < 216) ? 2 : (idx < 432) ? 4 : (idx < 648) ? 26
                   : (idx < 864) ? 28 : (idx < 900) ? 6 : 30;
            CTf[idx] = xs[ci] * w.x + xs[ci + 1] * w.y;
        }
        {   // Tk6: T10 / T20 linear
            const float4* W10 = (const float4*)(W + 6720);
            const float4* W20 = (const float4*)(W + 7296);
            for (int p = tid; p < 288; p += BLK) {
                float4 w = W10[p];
                float lo = xs[8]*w.x + xs[9]*w.y, hi = xs[8]*w.z + xs[9]*w.w;
                unsigned pk;
                asm("v_cvt_pk_bf16_f32 %0, %1, %2" : "=v"(pk) : "v"(lo), "v"(hi));
                *(unsigned*)&Tk6[p*2] = pk;
                w = W20[p];
                lo = xs[16]*w.x + xs[17]*w.y; hi = xs[16]*w.z + xs[17]*w.w;
                asm("v_cvt_pk_bf16_f32 %0, %1, %2" : "=v"(pk) : "v"(lo), "v"(hi));
                *(unsigned*)&Tk6[576 + p*2] = pk;
            }
        }
        BUILD2(TA, W + 0, 1008, xs[10], xs[11]);       // T11
        for (int idx = tid; idx < 432; idx += BLK) {   // TBt k-pads 36..47 zero
            int n = idx/12, k = 36 + idx%12;
            TBt[n*56 + k] = 0;
        }
    }
    __syncthreads();

    // ---- P2: chain step1 (M=6), n-paired, reads seeds from seedb ---------
    if (tid < 108) {
        int m = tid / 18, nn = (tid % 18) * 2;
        float a0e = 0.f, a0o = 0.f, a3e = 0.f, a3o = 0.f;
        #pragma unroll
        for (int k = 0; k < 6; ++k) {
            float e = b2f(seedb[m*6 + k]);
            float f = b2f(seedb[36 + m*6 + k]);
            a0e = fmaf(e, CTf[nn*6 + k],           a0e);
            a0o = fmaf(e, CTf[nn*6 + 6 + k],       a0o);
            a3e = fmaf(f, CTf[432 + nn*6 + k],     a3e);
            a3o = fmaf(f, CTf[432 + nn*6 + 6 + k], a3o);
        }
        int o = (m*6 + nn/6)*56 + nn%6;
        unsigned pk;
        asm("v_cvt_pk_bf16_f32 %0, %1, %2" : "=v"(pk) : "v"(a0e), "v"(a0o));
        *(unsigned*)&Ebuf[o + 12] = pk;
        asm("v_cvt_pk_bf16_f32 %0, %1, %2" : "=v"(pk) : "v"(a3e), "v"(a3o));
        *(unsigned*)&Ebuf[o + 24] = pk;
    }
    __syncthreads();

    // ---- P3: chain step2 (M=36), n-paired --------------------------------
    for (int p = tid; p < 648; p += BLK) {
        int m = p / 18, nn = (p % 18) * 2;
        float a0e = 0.f, a0o = 0.f, a3e = 0.f, a3o = 0.f;
        #pragma unroll
        for (int k = 0; k < 6; ++k) {
            float e = b2f(Ebuf[m*56 + 12 + k]);
            float f = b2f(Ebuf[m*56 + 24 + k]);
            a0e = fmaf(e, CTf[216 + nn*6 + k],     a0e);
            a0o = fmaf(e, CTf[216 + nn*6 + 6 + k], a0o);
            a3e = fmaf(f, CTf[648 + nn*6 + k],     a3e);
            a3o = fmaf(f, CTf[648 + nn*6 + 6 + k], a3o);
        }
        int o = (m*6 + nn/6)*56 + nn%6;
        unsigned pk;
        asm("v_cvt_pk_bf16_f32 %0, %1, %2" : "=v"(pk) : "v"(a0e), "v"(a0o));
        *(unsigned*)&Ebuf[o + 6] = pk;
        asm("v_cvt_pk_bf16_f32 %0, %1, %2" : "=v"(pk) : "v"(a3e), "v"(a3o));
        *(unsigned*)&Ebuf[o + 18] = pk;
    }
    __syncthreads();

    // ---- P4: chain tails, n-paired: band6 -> E0; band18 -> EBT bf16 ------
    for (int p = tid; p < 648; p += BLK) {
        int m = p / 3, nn = (p % 3) * 2;
        float a0e = 0.f, a0o = 0.f, a3e = 0.f, a3o = 0.f;
        #pragma unroll
        for (int k = 0; k < 6; ++k) {
            float e = b2f(Ebuf[m*56 + 6  + k]);
            float f = b2f(Ebuf[m*56 + 18 + k]);
            a0e = fmaf(e, CTf[864 + nn*6 + k],     a0e);
            a0o = fmaf(e, CTf[864 + nn*6 + 6 + k], a0o);
            a3e = fmaf(f, CTf[900 + nn*6 + k],     a3e);
            a3o = fmaf(f, CTf[900 + nn*6 + 6 + k], a3o);
        }
        unsigned pk;
        asm("v_cvt_pk_bf16_f32 %0, %1, %2" : "=v"(pk) : "v"(a0e), "v"(a0o));
        Ebuf[((m%36)*6 + nn)*56 + m/36]     = (unsigned short)pk;       // E0
        Ebuf[((m%36)*6 + nn + 1)*56 + m/36] = (unsigned short)(pk >> 16);
        asm("v_cvt_pk_bf16_f32 %0, %1, %2" : "=v"(pk) : "v"(a3e), "v"(a3o));
        TBt[((m%6)*6 + nn)*56 + m/6]        = (unsigned short)pk;       // EBT
        TBt[((m%6)*6 + nn + 1)*56 + m/6]    = (unsigned short)(pk >> 16);
    }
    __syncthreads();

    // ================= row 1 =================
    ACC0();
    MFMA_PHASE(1, 2, Tk6, 16);                               // P5: j=0 (T10)
    __syncthreads();
    SCAT(2, mtabA, ((n/6)*56 + n%6)*2);                      // P6
    BUILD2((unsigned short*)CTf, W + 6048, 168, xs[14], xs[15]);  // T13 overlay
    __syncthreads();
    ACC0();
    MFMA_PHASE(3, 2, TA, 56);                                // P7: j=1 (T11)
    __syncthreads();
    SCAT(2, mtabA, ((n/6)*56 + n%6)*2);                      // P8
    BUILD2(TA, W + 2016, 1008, xs[12], xs[13]);              // T12 (T11 dead)
    __syncthreads();
    ACC0();
    MFMA_PHASE(3, 2, TA, 56);                                // P9: j=2 (T12)
    __syncthreads();
    SCAT(2, mtabA, ((n/6)*56 + n%6)*2);                      // P10
    BUILD2(TA, W + 4032, 1008, xs[18], xs[19]);              // T21 (T12 dead)
    __syncthreads();
    ACC0();
    MFMA_PHASE(3, 1, (unsigned short*)CTf, 56);              // P11: j=3 (T13)
    __syncthreads();
    SCAT_D();                                                // P12: env_top
    BUILD2((unsigned short*)CTf, W + 6384, 168, xs[22], xs[23]);  // NT overlay
    __syncthreads();

    // ================= row 2 =================
    ACC0();
    MFMA_PHASE(1, 2, (Tk6 + 576), 16);                       // P13: j=0 (T20)
    __syncthreads();
    SCAT(2, mtabA, ((n/6)*56 + n%6)*2);                      // P14
    __syncthreads();
    ACC0();
    MFMA_PHASE(3, 2, TA, 56);                                // P15: j=1 (T21)
    __syncthreads();
    SCAT(2, mtabB, ((n%6)*56 + n/6)*2);                      // P16
    __syncthreads();
    ACC0();
    MFMA_PHASE(3, 2, TBt, 56);                               // P17: R = S_pre x EB
    __syncthreads();
    SCAT(2, mtabC, ((n/6)*56 + n%6)*2);                      // P18
    __syncthreads();
    ACC0();
    MFMA_PHASE(3, 1, (unsigned short*)CTf, 56);              // P19a: T1 (NT)
    __syncthreads();   // all Ebuf frag reads done before T1 overlays it
    SCATTER(1, 6, T1S[m*6 + n] = v);                         // P19b
    __syncthreads();

    // ---- P20: out[o] = sum T1 * (x20*C0 + x21*C1), PC pre-permuted -------
    float part[10];
    #pragma unroll
    for (int o = 0; o < 10; ++o) part[o] = 0.f;
    {
        const float* T1p = (const float*)Ebuf;
        for (int e = tid; e < 1296; e += BLK) {
            float t1 = T1p[e];
            #pragma unroll
            for (int o = 0; o < 10; ++o) {
                float c0 = PC[o * 1296 + e];
                float c1 = PC[(10 + o) * 1296 + e];
                part[o] = fmaf(t1, xs[20] * c0 + xs[21] * c1, part[o]);
            }
        }
    }
    #pragma unroll
    for (int off = 32; off >= 1; off >>= 1)
        #pragma unroll
        for (int o = 0; o < 10; ++o)
            part[o] += __shfl_down(part[o], off, 64);
    if (lid == 0) {
        #pragma unroll
        for (int o = 0; o < 10; ++o) red[wid * 10 + o] = part[o];
    }
    __syncthreads();
    if (tid < 10) {
        float s = 0.f;
        #pragma unroll
        for (int w = 0; w < 8; ++w) s += red[w * 10 + tid];
        red[80 + tid] = s;
    }
    __syncthreads();
    if (tid == 0) {
        float n2 = 0.f;
        #pragma unroll
        for (int o = 0; o < 10; ++o) n2 += red[80 + o] * red[80 + o];
        red[90] = 1.0f / sqrtf(n2);
    }
    __syncthreads();
    if (tid < 10) out[b0 * 10 + tid] = red[80 + tid] * red[90];
}

extern "C" void kernel_launch(void* const* d_in, const int* in_sizes, int n_in,
                              void* d_out, int out_size, void* d_ws, size_t ws_size,
                              hipStream_t stream) {
    const float* inputs = (const float*)d_in[0];   // (B,4,4,2) f32
    const float* peps   = (const float*)d_in[1];   // (4,4,2,6,6,6,6) f32
    const float* pepsc  = (const float*)d_in[2];   // (2,10,6,6,6,6) f32
    float* outp = (float*)d_out;                   // (B,10) f32
    float* ws   = (float*)d_ws;                    // >= 174,720 B used
    const int B = in_sizes[0] / 32;
    peps_prep<<<dim3(136), dim3(256), 0, stream>>>(peps, pepsc, ws);
    peps_fused<<<dim3(B), dim3(BLK), 0, stream>>>(inputs, ws, outp);
}

// Round 9
// 89.739 us; speedup vs baseline: 1.2902x; 1.0156x over previous
//
#include <hip/hip_runtime.h>
#include <math.h>

#define BLK 512

typedef __attribute__((ext_vector_type(8))) short s16x8;
typedef __attribute__((ext_vector_type(16))) float f32x16;
typedef __attribute__((ext_vector_type(4))) unsigned short u16x4;

__device__ __forceinline__ float b2f(unsigned short h) {
    union { unsigned u; float f; } x; x.u = ((unsigned)h) << 16; return x.f;
}
__device__ __forceinline__ unsigned short f2b(float f) {
    union { float f; unsigned u; } x; x.f = f;
    unsigned r = x.u + 0x7fffu + ((x.u >> 16) & 1u);
    return (unsigned short)(r >> 16);
}

#define SITE(i, j) (peps + (size_t)((i) * 4 + (j)) * 2 * 1296)

// ===================== prep kernel: one-time gather reorder =================
// Writes d_ws: W = float2[8880] of (a,c) weight pairs pre-gathered into the
// EXACT destination order of each LDS tile (pads pre-zeroed), then
// PC = float[25920] in TRANSPOSED [e][o] order (o=0..9 c0, o=10..19 c1, e in
// e6-permuted order) so P20 reads 5 float4 per element instead of 20 dwords.
// Layout (float2 units):
//  W11@0[2016] W12@2016 W21@4032 W13@6048[336] WNT@6384[336]
//  W10@6720[576] W20@7296[576] WCT@7872[936, k-minor n*6+k] WE0@8808[36]
//  WE3@8844[36]
__global__ __launch_bounds__(256)
void peps_prep(const float* __restrict__ peps, const float* __restrict__ pepsc,
               float* __restrict__ ws)
{
    int idx = blockIdx.x * 256 + threadIdx.x;
    float2* W = (float2*)ws;
    float* PC = ws + 2 * 8880;
    if (idx < 8880) {
        const float* s = peps;
        int g = -1;
        if (idx < 6048) {
            int seg = idx / 2016, i = idx - seg * 2016;
            int n = i / 56, k = i % 56;
            s = (seg == 0) ? SITE(1,1) : (seg == 1) ? SITE(1,2) : SITE(2,1);
            if (k < 36) g = (k/6)*216 + (k%6) + (n/6)*6 + (n%6)*36;
        } else if (idx < 6384) {
            int i = idx - 6048, n = i / 56, k = i % 56;
            s = SITE(1,3);
            if (k < 36) g = (k/6)*216 + (k%6) + n*6;
        } else if (idx < 6720) {
            int i = idx - 6384, n = i / 56, k = i % 56;
            s = SITE(2,3);
            if (k < 36) g = (k/6)*216 + (k%6)*6 + n;
        } else if (idx < 7872) {
            int i = idx - 6720; int w2 = i / 576; i -= w2 * 576;
            int n = i / 16, k = i % 16;
            s = w2 ? SITE(2,0) : SITE(1,0);
            if (k < 6) g = k*216 + (n/6)*6 + (n%6)*36;
        } else if (idx < 8808) {
            int i = idx - 7872;
            if (i < 864) {          // chain tiles, k-minor order [n*6+k]
                int seg = i / 216, j = i - seg * 216;
                int n = j / 6, k = j % 6;
                if (seg == 0)      { s = SITE(0,1); g = k + (n/6)*6   + (n%6)*36; }
                else if (seg == 1) { s = SITE(0,2); g = k + (n/6)*6   + (n%6)*36; }
                else if (seg == 2) { s = SITE(3,1); g = k + (n/6)*216 + (n%6)*36; }
                else               { s = SITE(3,2); g = k + (n/6)*216 + (n%6)*36; }
            } else {                // P4 tail tiles, k-minor [n*6+k]
                int j = i - 864, seg = j / 36, t = j % 36;
                int n = t / 6, k = t % 6;
                if (seg == 0) { s = SITE(0,3); g = k + n*6; }
                else          { s = SITE(3,3); g = k + n*216; }
            }
        } else if (idx < 8844) {
            int i = idx - 8808; s = SITE(0,0); g = (i%6)*36 + (i/6)*6;
        } else {
            int i = idx - 8844; s = SITE(3,0); g = (i/6)*216 + (i%6)*36;
        }
        float a = 0.f, c = 0.f;
        if (g >= 0) { a = s[g]; c = s[g + 1296]; }
        W[idx] = make_float2(a, c);
    } else if (idx < 8880 + 25920) {
        int i = idx - 8880;
        int e = i / 20, o = i % 20;                 // TRANSPOSED [e][o]
        int u2 = e / 216, r1 = (e / 36) % 6, d2 = (e / 6) % 6, r2 = e % 6;
        PC[i] = pepsc[o * 1296 + u2*216 + r2*36 + d2*6 + r1];
    }
}

// ======================= MFMA config (proven layout) ========================
// A=env (lane->m), B=tile (lane->n via rows nt*4+col), C/D: col(lane)=n,
// row=(reg&3)+8*(reg>>2)+4*(lane>>5) [m74/m101]. 8 waves/block: wave w<7 owns
// Mtile w (Mtile6 base 184, dedup keeps m>=192 == skip rr=0); wave 7 idle in
// MFMA. acc[2]=32 AGPR; launch_bounds(512,8) caps unified regs at 64.
// LDS 40688 B -> block size 40960 -> 4 blocks/CU; grid 1024 = one round.

#define MFMA_PHASE(NKB, NNT, TB, TSTR) do {                                    \
    if (wid < 7) {                                                             \
        int m0 = (wid == 6) ? 184 : wid*32;                                    \
        _Pragma("unroll") for (int kb = 0; kb < NKB; ++kb) {                   \
            s16x8 _av = *(const s16x8*)&Ebuf[(m0 + col)*56 + kb*16 + q*8];     \
            _Pragma("unroll") for (int nt = 0; nt < NNT; ++nt) {               \
                s16x8 _bf = *(const s16x8*)&(TB)[(nt*4 + col)*(TSTR) + kb*16 + q*8]; \
                acc[nt] = __builtin_amdgcn_mfma_f32_32x32x16_bf16(             \
                    _av, _bf, acc[nt], 0, 0, 0);                               \
            } } } } while (0)

// Fast scatter: off_bytes = mtab[m] + NOFFE(n); cvt_pk pairs (RNE == f2b).
#define SCAT(NNT, MTAB, NOFFE) do {                                            \
    if (wid < 7) {                                                             \
        int mbase = ((wid == 6) ? 184 : wid*32) + 4*q;                         \
        int noffv[2]; bool okv[2];                                             \
        _Pragma("unroll") for (int nt = 0; nt < NNT; ++nt) {                   \
            int n = nt*4 + col;                                                \
            noffv[nt] = (NOFFE);                                               \
            okv[nt]   = (nt == 0) || (n >= 32);                                \
        }                                                                      \
        _Pragma("unroll") for (int rr = 0; rr < 4; ++rr) {                     \
            if (wid == 6 && rr == 0) continue;                                 \
            u16x4 mt4 = *(const u16x4*)&(MTAB)[mbase + 8*rr];                  \
            _Pragma("unroll") for (int nt = 0; nt < NNT; ++nt) {               \
                _Pragma("unroll") for (int jp = 0; jp < 2; ++jp) {             \
                    unsigned pk;                                               \
                    float _lo = acc[nt][rr*4 + jp*2];                          \
                    float _hi = acc[nt][rr*4 + jp*2 + 1];                      \
                    asm("v_cvt_pk_bf16_f32 %0, %1, %2"                         \
                        : "=v"(pk) : "v"(_lo), "v"(_hi));                      \
                    if (okv[nt]) {                                             \
                        *(unsigned short*)((char*)Ebuf + (int)mt4[jp*2]   + noffv[nt]) = (unsigned short)pk;         \
                        *(unsigned short*)((char*)Ebuf + (int)mt4[jp*2+1] + noffv[nt]) = (unsigned short)(pk >> 16); \
                    } } } } } } while (0)

// P12 variant: nt=0 only, keep n<6, noff = n*112 bytes, table D.
#define SCAT_D() do {                                                          \
    if (wid < 7) {                                                             \
        int mbase = ((wid == 6) ? 184 : wid*32) + 4*q;                         \
        bool ok = (col < 6);                                                   \
        int noff = col * 112;                                                  \
        _Pragma("unroll") for (int rr = 0; rr < 4; ++rr) {                     \
            if (wid == 6 && rr == 0) continue;                                 \
            u16x4 mt4 = *(const u16x4*)&mtabD[mbase + 8*rr];                   \
            _Pragma("unroll") for (int jp = 0; jp < 2; ++jp) {                 \
                unsigned pk;                                                   \
                float _lo = acc[0][rr*4 + jp*2];                               \
                float _hi = acc[0][rr*4 + jp*2 + 1];                           \
                asm("v_cvt_pk_bf16_f32 %0, %1, %2"                             \
                    : "=v"(pk) : "v"(_lo), "v"(_hi));                          \
                if (ok) {                                                      \
                    *(unsigned short*)((char*)Ebuf + (int)mt4[jp*2]   + noff) = (unsigned short)pk;         \
                    *(unsigned short*)((char*)Ebuf + (int)mt4[jp*2+1] + noff) = (unsigned short)(pk >> 16); \
                } } } } } while (0)

// Generic scatter kept for P19b (float writes, affine index, cheap).
#define SCATTER(NNT, NLIM, PUT) do {                                           \
    unsigned short* EbS = Ebuf;                                                \
    float* T1S = (float*)Ebuf; (void)EbS; (void)T1S;                           \
    if (wid < 7) {                                                             \
        int m0 = (wid == 6) ? 184 : wid*32;                                    \
        _Pragma("unroll") for (int nt = 0; nt < NNT; ++nt) {                   \
            int n = nt*4 + col;                                                \
            if ((NNT == 2 && nt == 1 && n < 32) || n >= NLIM) continue;        \
            _Pragma("unroll") for (int r = 0; r < 16; ++r) {                   \
                int m = m0 + (r&3) + 8*(r>>2) + 4*q;                           \
                if (wid == 6 && m < 192) continue;                             \
                float v = acc[nt][r];                                          \
                PUT;                                                           \
            } } } } while (0)

#define ACC0() do {                                                            \
    _Pragma("unroll") for (int nt = 0; nt < 2; ++nt)                           \
    _Pragma("unroll") for (int r = 0; r < 16; ++r) acc[nt][r] = 0.f;           \
    } while (0)

// Linear build: DST u16 tile <- cvt_pk(X0*w.xz + X1*w.yw) over NPAIR float4.
#define BUILD2(DST, SRCF2, NPAIR, X0, X1) do {                                 \
    const float4* _w4 = (const float4*)(SRCF2);                                \
    for (int p = tid; p < (NPAIR); p += BLK) {                                 \
        float4 w = _w4[p];                                                     \
        float _lo = (X0)*w.x + (X1)*w.y, _hi = (X0)*w.z + (X1)*w.w;            \
        unsigned pk;                                                           \
        asm("v_cvt_pk_bf16_f32 %0, %1, %2" : "=v"(pk) : "v"(_lo), "v"(_hi));   \
        *(unsigned*)&(DST)[p*2] = pk;                                          \
    } } while (0)

__global__ __launch_bounds__(BLK, 8)
void peps_fused(const float* __restrict__ inputs,
                const float* __restrict__ ws,
                float* __restrict__ out)
{
    __shared__ __align__(16) unsigned short Ebuf[216 * 56];  // env bf16 [m][56]
    __shared__ __align__(16) unsigned short TA[36 * 56];     // rotating big tile
    __shared__ __align__(16) unsigned short TBt[36 * 56];    // EBT tile
    __shared__ __align__(16) unsigned short Tk6[2 * 36 * 16];// T10, T20
    __shared__ __align__(16) float CTf[936];                 // chain tiles (k-minor) / overlays
    __shared__ __align__(8) unsigned short mtabA[216];       // scatter m-offset tables (bytes)
    __shared__ __align__(8) unsigned short mtabB[216];
    __shared__ __align__(8) unsigned short mtabC[216];
    __shared__ __align__(8) unsigned short mtabD[216];
    __shared__ __align__(8) unsigned short seedb[72];        // E0/E3 chain seeds (bf16)
    __shared__ float xs[32];
    __shared__ float red[96];

    const int b0  = blockIdx.x;
    const int tid = threadIdx.x;
    const int lid = tid & 63;
    const int q   = lid >> 5;
    const int col = lid & 31;
    // wave-uniform by construction (BLK multiple of 64) -> force SGPR
    const int wid = __builtin_amdgcn_readfirstlane(tid >> 6);

    const float2* W = (const float2*)ws;
    const float*  PC = ws + 2 * 8880;

    f32x16 acc[2];

    // ---- P0 (merged): xs per-wave (same-wave LDS in-order => no barrier
    //      needed before in-phase xs reads; duplicate identical writes are
    //      benign), zero Ebuf, scatter tables, seeds->seedb, ALL tile builds.
    {
        if (lid < 32) xs[lid] = inputs[b0 * 32 + lid] * 100.0f;
        uint4* ez = (uint4*)&Ebuf[0];
        const uint4 z = make_uint4(0u, 0u, 0u, 0u);
        for (int i2 = tid; i2 < 1512; i2 += BLK) ez[i2] = z;
        if (tid < 216) {
            int m = tid;
            mtabA[m] = (unsigned short)(((m%36)*336 + (m/36)*6) * 2);
            mtabB[m] = (unsigned short)(((m/6)*336 + (m%6)*6) * 2);
            mtabC[m] = (unsigned short)(((m/36)*2016 + (m%6)*336 + ((m/6)%6)*6) * 2);
            mtabD[m] = (unsigned short)(((m%36)*336 + (m/36)) * 2);
        }
        if (tid < 36) {                            // chain seeds (bf16, bit-exact)
            float2 w0 = W[8808 + tid], w3 = W[8844 + tid];
            seedb[tid]      = f2b(xs[0]  * w0.x + xs[1]  * w0.y);
            seedb[36 + tid] = f2b(xs[24] * w3.x + xs[25] * w3.y);
        }
        for (int idx = tid; idx < 936; idx += BLK) {   // CTf (f32, k-minor)
            float2 w = W[7872 + idx];
            int ci = (idx < 216) ? 2 : (idx < 432) ? 4 : (idx < 648) ? 26
                   : (idx < 864) ? 28 : (idx < 900) ? 6 : 30;
            CTf[idx] = xs[ci] * w.x + xs[ci + 1] * w.y;
        }
        {   // Tk6: T10 / T20 linear
            const float4* W10 = (const float4*)(W + 6720);
            const float4* W20 = (const float4*)(W + 7296);
            for (int p = tid; p < 288; p += BLK) {
                float4 w = W10[p];
                float lo = xs[8]*w.x + xs[9]*w.y, hi = xs[8]*w.z + xs[9]*w.w;
                unsigned pk;
                asm("v_cvt_pk_bf16_f32 %0, %1, %2" : "=v"(pk) : "v"(lo), "v"(hi));
                *(unsigned*)&Tk6[p*2] = pk;
                w = W20[p];
                lo = xs[16]*w.x + xs[17]*w.y; hi = xs[16]*w.z + xs[17]*w.w;
                asm("v_cvt_pk_bf16_f32 %0, %1, %2" : "=v"(pk) : "v"(lo), "v"(hi));
                *(unsigned*)&Tk6[576 + p*2] = pk;
            }
        }
        BUILD2(TA, W + 0, 1008, xs[10], xs[11]);       // T11
        for (int idx = tid; idx < 432; idx += BLK) {   // TBt k-pads 36..47 zero
            int n = idx/12, k = 36 + idx%12;
            TBt[n*56 + k] = 0;
        }
    }
    __syncthreads();

    // ---- P2: chain step1 (M=6), n-paired, reads seeds from seedb ---------
    if (tid < 108) {
        int m = tid / 18, nn = (tid % 18) * 2;
        float a0e = 0.f, a0o = 0.f, a3e = 0.f, a3o = 0.f;
        #pragma unroll
        for (int k = 0; k < 6; ++k) {
            float e = b2f(seedb[m*6 + k]);
            float f = b2f(seedb[36 + m*6 + k]);
            a0e = fmaf(e, CTf[nn*6 + k],           a0e);
            a0o = fmaf(e, CTf[nn*6 + 6 + k],       a0o);
            a3e = fmaf(f, CTf[432 + nn*6 + k],     a3e);
            a3o = fmaf(f, CTf[432 + nn*6 + 6 + k], a3o);
        }
        int o = (m*6 + nn/6)*56 + nn%6;
        unsigned pk;
        asm("v_cvt_pk_bf16_f32 %0, %1, %2" : "=v"(pk) : "v"(a0e), "v"(a0o));
        *(unsigned*)&Ebuf[o + 12] = pk;
        asm("v_cvt_pk_bf16_f32 %0, %1, %2" : "=v"(pk) : "v"(a3e), "v"(a3o));
        *(unsigned*)&Ebuf[o + 24] = pk;
    }
    __syncthreads();

    // ---- P3: chain step2 (M=36), n-paired --------------------------------
    for (int p = tid; p < 648; p += BLK) {
        int m = p / 18, nn = (p % 18) * 2;
        float a0e = 0.f, a0o = 0.f, a3e = 0.f, a3o = 0.f;
        #pragma unroll
        for (int k = 0; k < 6; ++k) {
            float e = b2f(Ebuf[m*56 + 12 + k]);
            float f = b2f(Ebuf[m*56 + 24 + k]);
            a0e = fmaf(e, CTf[216 + nn*6 + k],     a0e);
            a0o = fmaf(e, CTf[216 + nn*6 + 6 + k], a0o);
            a3e = fmaf(f, CTf[648 + nn*6 + k],     a3e);
            a3o = fmaf(f, CTf[648 + nn*6 + 6 + k], a3o);
        }
        int o = (m*6 + nn/6)*56 + nn%6;
        unsigned pk;
        asm("v_cvt_pk_bf16_f32 %0, %1, %2" : "=v"(pk) : "v"(a0e), "v"(a0o));
        *(unsigned*)&Ebuf[o + 6] = pk;
        asm("v_cvt_pk_bf16_f32 %0, %1, %2" : "=v"(pk) : "v"(a3e), "v"(a3o));
        *(unsigned*)&Ebuf[o + 18] = pk;
    }
    __syncthreads();

    // ---- P4: chain tails, n-paired: band6 -> E0; band18 -> EBT bf16 ------
    for (int p = tid; p < 648; p += BLK) {
        int m = p / 3, nn = (p % 3) * 2;
        float a0e = 0.f, a0o = 0.f, a3e = 0.f, a3o = 0.f;
        #pragma unroll
        for (int k = 0; k < 6; ++k) {
            float e = b2f(Ebuf[m*56 + 6  + k]);
            float f = b2f(Ebuf[m*56 + 18 + k]);
            a0e = fmaf(e, CTf[864 + nn*6 + k],     a0e);
            a0o = fmaf(e, CTf[864 + nn*6 + 6 + k], a0o);
            a3e = fmaf(f, CTf[900 + nn*6 + k],     a3e);
            a3o = fmaf(f, CTf[900 + nn*6 + 6 + k], a3o);
        }
        unsigned pk;
        asm("v_cvt_pk_bf16_f32 %0, %1, %2" : "=v"(pk) : "v"(a0e), "v"(a0o));
        Ebuf[((m%36)*6 + nn)*56 + m/36]     = (unsigned short)pk;       // E0
        Ebuf[((m%36)*6 + nn + 1)*56 + m/36] = (unsigned short)(pk >> 16);
        asm("v_cvt_pk_bf16_f32 %0, %1, %2" : "=v"(pk) : "v"(a3e), "v"(a3o));
        TBt[((m%6)*6 + nn)*56 + m/6]        = (unsigned short)pk;       // EBT
        TBt[((m%6)*6 + nn + 1)*56 + m/6]    = (unsigned short)(pk >> 16);
    }
    __syncthreads();

    // ================= row 1 =================
    ACC0();
    MFMA_PHASE(1, 2, Tk6, 16);                               // P5: j=0 (T10)
    __syncthreads();
    SCAT(2, mtabA, ((n/6)*56 + n%6)*2);                      // P6
    BUILD2((unsigned short*)CTf, W + 6048, 168, xs[14], xs[15]);  // T13 overlay
    __syncthreads();
    ACC0();
    MFMA_PHASE(3, 2, TA, 56);                                // P7: j=1 (T11)
    __syncthreads();
    SCAT(2, mtabA, ((n/6)*56 + n%6)*2);                      // P8
    BUILD2(TA, W + 2016, 1008, xs[12], xs[13]);              // T12 (T11 dead)
    __syncthreads();
    ACC0();
    MFMA_PHASE(3, 2, TA, 56);                                // P9: j=2 (T12)
    __syncthreads();
    SCAT(2, mtabA, ((n/6)*56 + n%6)*2);                      // P10
    BUILD2(TA, W + 4032, 1008, xs[18], xs[19]);              // T21 (T12 dead)
    __syncthreads();
    ACC0();
    MFMA_PHASE(3, 1, (unsigned short*)CTf, 56);              // P11: j=3 (T13)
    __syncthreads();
    SCAT_D();                                                // P12: env_top
    BUILD2((unsigned short*)CTf, W + 6384, 168, xs[22], xs[23]);  // NT overlay
    __syncthreads();

    // ================= row 2 =================
    ACC0();
    MFMA_PHASE(1, 2, (Tk6 + 576), 16);                       // P13: j=0 (T20)
    __syncthreads();
    SCAT(2, mtabA, ((n/6)*56 + n%6)*2);                      // P14
    __syncthreads();
    ACC0();
    MFMA_PHASE(3, 2, TA, 56);                                // P15: j=1 (T21)
    __syncthreads();
    SCAT(2, mtabB, ((n%6)*56 + n/6)*2);                      // P16
    __syncthreads();
    ACC0();
    MFMA_PHASE(3, 2, TBt, 56);                               // P17: R = S_pre x EB
    __syncthreads();
    SCAT(2, mtabC, ((n/6)*56 + n%6)*2);                      // P18
    __syncthreads();
    ACC0();
    MFMA_PHASE(3, 1, (unsigned short*)CTf, 56);              // P19a: T1 (NT)
    __syncthreads();   // all Ebuf frag reads done before T1 overlays it
    SCATTER(1, 6, T1S[m*6 + n] = v);                         // P19b
    __syncthreads();

    // ---- P20: out[o] = sum T1 * (x20*C0 + x21*C1), PC transposed [e][20] -
    float part[10];
    #pragma unroll
    for (int o = 0; o < 10; ++o) part[o] = 0.f;
    {
        const float* T1p = (const float*)Ebuf;
        for (int e = tid; e < 1296; e += BLK) {
            float t1 = T1p[e];
            const float4* pc4 = (const float4*)(PC + e * 20);
            float arr[20];
            #pragma unroll
            for (int j = 0; j < 5; ++j) *(float4*)&arr[j*4] = pc4[j];
            #pragma unroll
            for (int o = 0; o < 10; ++o)
                part[o] = fmaf(t1, xs[20] * arr[o] + xs[21] * arr[10 + o], part[o]);
        }
    }
    #pragma unroll
    for (int off = 32; off >= 1; off >>= 1)
        #pragma unroll
        for (int o = 0; o < 10; ++o)
            part[o] += __shfl_down(part[o], off, 64);
    if (lid == 0) {
        #pragma unroll
        for (int o = 0; o < 10; ++o) red[wid * 10 + o] = part[o];
    }
    __syncthreads();
    if (tid < 10) {
        float s = 0.f;
        #pragma unroll
        for (int w = 0; w < 8; ++w) s += red[w * 10 + tid];
        red[80 + tid] = s;
    }
    __syncthreads();
    if (tid == 0) {
        float n2 = 0.f;
        #pragma unroll
        for (int o = 0; o < 10; ++o) n2 += red[80 + o] * red[80 + o];
        red[90] = 1.0f / sqrtf(n2);
    }
    __syncthreads();
    if (tid < 10) out[b0 * 10 + tid] = red[80 + tid] * red[90];
}

extern "C" void kernel_launch(void* const* d_in, const int* in_sizes, int n_in,
                              void* d_out, int out_size, void* d_ws, size_t ws_size,
                              hipStream_t stream) {
    const float* inputs = (const float*)d_in[0];   // (B,4,4,2) f32
    const float* peps   = (const float*)d_in[1];   // (4,4,2,6,6,6,6) f32
    const float* pepsc  = (const float*)d_in[2];   // (2,10,6,6,6,6) f32
    float* outp = (float*)d_out;                   // (B,10) f32
    float* ws   = (float*)d_ws;                    // >= 174,720 B used
    const int B = in_sizes[0] / 32;
    peps_prep<<<dim3(136), dim3(256), 0, stream>>>(peps, pepsc, ws);
    peps_fused<<<dim3(B), dim3(BLK), 0, stream>>>(inputs, ws, outp);
}